// Round 16
// baseline (1841.379 us; speedup 1.0000x reference)
//
#include <hip/hip_runtime.h>
#include <hip/hip_bf16.h>
#include <math.h>

// Problem constants
#define BB 32
#define LL 1024
#define C_IN 21
#define DM 256
#define DFF 1024
#define NLAYERS 3
#define TOPK 6
#define TOPC 16
#define LSCALE 4096.0f
#define LINV (1.0f/4096.0f)

typedef __attribute__((ext_vector_type(8))) short short8v;
typedef __attribute__((ext_vector_type(8))) _Float16 half8;
typedef __attribute__((ext_vector_type(4))) float f32x4;

__device__ __forceinline__ float gelu_f(float v){
    return 0.5f * v * (1.0f + erff(v * 0.7071067811865476f));
}
__device__ __forceinline__ ushort f2h_bits(float f){
    _Float16 h = (_Float16)f;
    return __builtin_bit_cast(ushort, h);
}
__device__ __forceinline__ float h2f(ushort u){
    return (float)__builtin_bit_cast(_Float16, u);
}
// direct global->LDS 16B copy (wave-uniform LDS base + lane*16)
__device__ __forceinline__ void lds16(const ushort* g, ushort* l){
    __builtin_amdgcn_global_load_lds(
        (const __attribute__((address_space(1))) void*)g,
        (__attribute__((address_space(3))) void*)l, 16, 0, 0);
}
// split-pair helpers (4 elements)
__device__ __forceinline__ float4 loadp4(const ushort* __restrict__ h, const ushort* __restrict__ l, size_t i4){
    ushort4 hv = *reinterpret_cast<const ushort4*>(h + 4*i4);
    ushort4 lv = *reinterpret_cast<const ushort4*>(l + 4*i4);
    return make_float4(h2f(hv.x)+h2f(lv.x)*LINV, h2f(hv.y)+h2f(lv.y)*LINV,
                       h2f(hv.z)+h2f(lv.z)*LINV, h2f(hv.w)+h2f(lv.w)*LINV);
}
__device__ __forceinline__ void storep4(ushort* __restrict__ h, ushort* __restrict__ l, size_t i4, float4 v){
    ushort4 hv, lv;
    _Float16 a;
    a=(_Float16)v.x; hv.x=__builtin_bit_cast(ushort,a); lv.x=f2h_bits((v.x-(float)a)*LSCALE);
    a=(_Float16)v.y; hv.y=__builtin_bit_cast(ushort,a); lv.y=f2h_bits((v.y-(float)a)*LSCALE);
    a=(_Float16)v.z; hv.z=__builtin_bit_cast(ushort,a); lv.z=f2h_bits((v.z-(float)a)*LSCALE);
    a=(_Float16)v.w; hv.w=__builtin_bit_cast(ushort,a); lv.w=f2h_bits((v.w-(float)a)*LSCALE);
    *reinterpret_cast<ushort4*>(h + 4*i4) = hv;
    *reinterpret_cast<ushort4*>(l + 4*i4) = lv;
}

// ---------------- weight conversion: f16 hi + 4096*lo ----------------
__global__ __launch_bounds__(256) void split_w_k(const float* __restrict__ src,
                                                 ushort* __restrict__ h, ushort* __restrict__ l, int n){
    int i = blockIdx.x*256 + threadIdx.x;
    if (i < n){
        float f = src[i];
        _Float16 hh = (_Float16)f;
        h[i] = __builtin_bit_cast(ushort, hh);
        l[i] = f2h_bits((f - (float)hh) * LSCALE);
    }
}
__global__ __launch_bounds__(256) void split_w_strided(const float* __restrict__ src,
                                                       ushort* __restrict__ h, ushort* __restrict__ l,
                                                       int n, int src_ls, int dst_ls, int dst_off){
    int i = blockIdx.x*256 + threadIdx.x;
    if (i < n){
        int layer = i / src_ls, r = i % src_ls;
        float f = src[i];
        _Float16 hh = (_Float16)f;
        size_t d = (size_t)layer*dst_ls + dst_off + r;
        h[d] = __builtin_bit_cast(ushort, hh);
        l[d] = f2h_bits((f - (float)hh) * LSCALE);
    }
}
__global__ __launch_bounds__(256) void cat_bias_k(const float* __restrict__ b1,
                                                  const float* __restrict__ b2,
                                                  float* __restrict__ out, int n){
    int i = blockIdx.x*256 + threadIdx.x;
    if (i < n){
        int layer = i / 512, c = i % 512;
        out[i] = (c < 256) ? b1[layer*256 + c] : b2[layer*256 + c - 256];
    }
}
// transpose token weight [256][63] -> [63][256]
__global__ __launch_bounds__(256) void transpose_tw(const float* __restrict__ src,
                                                    float* __restrict__ dst){
    int i = blockIdx.x*256 + threadIdx.x;
    if (i < 256*63){
        int d = i / 63, k = i % 63;
        dst[k*256 + d] = src[i];
    }
}

// ---------------- token embedding: circular conv1d k=3, split-pair output ----------------
__global__ __launch_bounds__(256) void token_embed_k(const float* __restrict__ x,
                                                     const float* __restrict__ wT,
                                                     ushort* __restrict__ oh,
                                                     ushort* __restrict__ ol){
    int b = blockIdx.x, l0 = blockIdx.y*32;
    int d = threadIdx.x;
    __shared__ float xs[34][C_IN];
    for (int i = threadIdx.x; i < 34*C_IN; i += 256){
        int r = i / C_IN, c = i % C_IN;
        int g = (l0 - 1 + r + LL) & (LL-1);
        xs[r][c] = x[(size_t)b*LL*C_IN + (size_t)g*C_IN + c];
    }
    float w[63];
    #pragma unroll
    for (int k=0;k<63;k++) w[k] = wT[k*256 + d];
    __syncthreads();
    for (int i=0;i<32;i++){
        float acc = 0.f;
        #pragma unroll
        for (int c=0;c<C_IN;c++){
            acc += xs[i][c]   * w[c*3+0];
            acc += xs[i+1][c] * w[c*3+1];
            acc += xs[i+2][c] * w[c*3+2];
        }
        size_t idx = ((size_t)b*LL + l0+i)*DM + d;
        _Float16 hh = (_Float16)acc;
        oh[idx] = __builtin_bit_cast(ushort, hh);
        ol[idx] = f2h_bits((acc - (float)hh) * LSCALE);
    }
}

// =================== split-f16 MFMA GEMM, block 128x64, global_load_lds staging ===================
// LDS dest is linear (lane-ordered); global source is pre-swizzled (XOR involution) ->
// LDS contents bit-identical to the r15 reg-staged version.
// OMODE: 0 = f32 out (Cv), 2 = split pair out (Cv,C2v), 3 = qk dual split pair
template<bool BIAS, bool GELU, int OMODE, bool ZSPLIT>
__global__ __launch_bounds__(256) void gemm_mfma_split(const ushort* __restrict__ Ah_g,
                                                       const ushort* __restrict__ Al_g,
                                                       const ushort* __restrict__ Wh,
                                                       const ushort* __restrict__ Wl,
                                                       const float* __restrict__ bias,
                                                       void* __restrict__ Cv,
                                                       void* __restrict__ C2v,
                                                       void* __restrict__ C3v,
                                                       void* __restrict__ C4v,
                                                       int M, int N, int K){
    __shared__ __align__(16) ushort Ah_s[128*32];
    __shared__ __align__(16) ushort Al_s[128*32];
    __shared__ __align__(16) ushort Wh_s[64*32];
    __shared__ __align__(16) ushort Wl_s[64*32];

    const int tid = threadIdx.x;
    const int MB = M >> 7;
    const int bx = blockIdx.x % MB, by = blockIdx.x / MB;
    const int bm = bx << 7, bn = by << 6;

    const int lane = tid & 63;
    const int wid  = tid >> 6;
    const int wm = wid >> 1, wn = wid & 1;
    const int lr = lane & 15, lg = lane >> 4;

    int aoff[4], boff[2];
    #pragma unroll
    for (int f=0; f<4; f++){
        int ar = wm*64 + f*16 + lr;
        aoff[f] = ar*32 + (lg ^ ((ar>>1)&3))*8;
    }
    #pragma unroll
    for (int g=0; g<2; g++){
        int br = wn*32 + g*16 + lr;
        boff[g] = br*32 + (lg ^ ((br>>1)&3))*8;
    }

    f32x4 acc[4][2], accX[4][2];
    #pragma unroll
    for (int i=0;i<4;i++)
        #pragma unroll
        for (int j=0;j<2;j++){
            acc[i][j]  = (f32x4){0.f,0.f,0.f,0.f};
            accX[i][j] = (f32x4){0.f,0.f,0.f,0.f};
        }

    const int kbeg = ZSPLIT ? (int)blockIdx.y * (K>>1) : 0;
    const int kend = ZSPLIT ? kbeg + (K>>1) : K;
    const int wbase = (tid & 192);   // wave-uniform

    for (int k0=kbeg; k0<kend; k0+=32){
        // ---- stage A pair: direct global->LDS, pre-swizzled source ----
        #pragma unroll
        for (int i=0;i<2;i++){
            int c = i*256 + tid;
            int row = c >> 2, ko = c & 3;
            int sw = ko ^ ((row>>1)&3);
            size_t src = (size_t)(bm+row)*K + k0 + sw*8;
            int ldso = (i*256 + wbase)*8;
            lds16(Ah_g + src, &Ah_s[ldso]);
            lds16(Al_g + src, &Al_s[ldso]);
        }
        // ---- stage W pair ----
        {
            int row = tid >> 2, ko = tid & 3;
            int sw = ko ^ ((row>>1)&3);
            size_t src = (size_t)(bn+row)*K + k0 + sw*8;
            int ldso = wbase*8;
            lds16(Wh + src, &Wh_s[ldso]);
            lds16(Wl + src, &Wl_s[ldso]);
        }
        __syncthreads();

        short8v af[4], al[4], bf_[2], bl[2];
        #pragma unroll
        for (int f=0; f<4; f++){
            af[f] = *reinterpret_cast<short8v*>(&Ah_s[aoff[f]]);
            al[f] = *reinterpret_cast<short8v*>(&Al_s[aoff[f]]);
        }
        #pragma unroll
        for (int g=0; g<2; g++){
            bf_[g] = *reinterpret_cast<short8v*>(&Wh_s[boff[g]]);
            bl[g]  = *reinterpret_cast<short8v*>(&Wl_s[boff[g]]);
        }
        #pragma unroll
        for (int i=0;i<4;i++){
            #pragma unroll
            for (int j=0;j<2;j++){
                acc[i][j] = __builtin_amdgcn_mfma_f32_16x16x32_f16(
                    __builtin_bit_cast(half8, af[i]), __builtin_bit_cast(half8, bf_[j]), acc[i][j], 0,0,0);
                accX[i][j] = __builtin_amdgcn_mfma_f32_16x16x32_f16(
                    __builtin_bit_cast(half8, af[i]), __builtin_bit_cast(half8, bl[j]), accX[i][j], 0,0,0);
                accX[i][j] = __builtin_amdgcn_mfma_f32_16x16x32_f16(
                    __builtin_bit_cast(half8, al[i]), __builtin_bit_cast(half8, bf_[j]), accX[i][j], 0,0,0);
            }
        }
        __syncthreads();
    }

    // ---- epilogue ----
    float* Cout0 = (float*)((ZSPLIT && blockIdx.y) ? C2v : Cv);
    const int crow0 = bm + wm*64, ccol0 = bn + wn*32;
    #pragma unroll
    for (int i=0;i<4;i++){
        #pragma unroll
        for (int j=0;j<2;j++){
            int row0 = crow0 + i*16 + lg*4;
            int col  = ccol0 + j*16 + lr;
            float bv = (BIAS && (!ZSPLIT || blockIdx.y==0)) ? bias[col] : 0.f;
            #pragma unroll
            for (int r=0;r<4;r++){
                float v = acc[i][j][r] + accX[i][j][r]*LINV + bv;
                if (GELU) v = gelu_f(v);
                if (OMODE == 0){
                    Cout0[(size_t)(row0+r)*N + col] = v;
                } else if (OMODE == 2){
                    size_t idx = (size_t)(row0+r)*N + col;
                    _Float16 hh = (_Float16)v;
                    ((ushort*)Cv)[idx]  = __builtin_bit_cast(ushort, hh);
                    ((ushort*)C2v)[idx] = f2h_bits((v - (float)hh) * LSCALE);
                } else { // OMODE 3: qk dual pair, out stride 256
                    _Float16 hh = (_Float16)v;
                    ushort hb = __builtin_bit_cast(ushort, hh);
                    ushort lb = f2h_bits((v - (float)hh) * LSCALE);
                    if (col < 256){
                        size_t idx = (size_t)(row0+r)*256 + col;
                        ((ushort*)Cv)[idx]  = hb;
                        ((ushort*)C2v)[idx] = lb;
                    } else {
                        size_t idx = (size_t)(row0+r)*256 + (col-256);
                        ((ushort*)C3v)[idx] = hb;
                        ((ushort*)C4v)[idx] = lb;
                    }
                }
            }
        }
    }
}

// =================== corr (APPROX, hi-plane only): 128x128 Gram tile, global_load_lds staging ===================
__global__ __launch_bounds__(256) void corr_mfma(const ushort* __restrict__ qh,
                                                 const ushort* __restrict__ kh,
                                                 float* __restrict__ scr){
    __shared__ __align__(16) ushort Qh_s[128*32];
    __shared__ __align__(16) ushort Kh_s[128*32];
    __shared__ float bins[255];

    const int tid = threadIdx.x;
    int flat = blockIdx.x;
    flat = (flat & 7) * 256 + (flat >> 3);   // XCD-aware swizzle
    const int bxt = flat & 7;
    const int byt = (flat >> 3) & 7;
    const int b   = flat >> 6;
    const int bi = bxt * 128, bj = byt * 128;

    for (int i=tid; i<255; i+=256) bins[i] = 0.f;

    const int lane = tid & 63;
    const int wid  = tid >> 6;
    const int wm = wid >> 1, wn = wid & 1;
    const int lr = lane & 15, lg = lane >> 4;

    int aoff[4], boff[4];
    #pragma unroll
    for (int f=0; f<4; f++){
        int ar = wm*64 + f*16 + lr;
        aoff[f] = ar*32 + (lg ^ ((ar>>1)&3))*8;
        int br = wn*64 + f*16 + lr;
        boff[f] = br*32 + (lg ^ ((br>>1)&3))*8;
    }

    f32x4 acc[4][4];
    #pragma unroll
    for (int i=0;i<4;i++)
        #pragma unroll
        for (int j=0;j<4;j++)
            acc[i][j] = (f32x4){0.f,0.f,0.f,0.f};

    const size_t qbase = (size_t)b*LL*DM;
    const int wbase = (tid & 192);

    for (int k0=0; k0<DM; k0+=32){
        #pragma unroll
        for (int i=0;i<2;i++){
            int c = i*256 + tid;
            int row = c >> 2, ko = c & 3;
            int sw = ko ^ ((row>>1)&3);
            size_t qsrc = qbase + (size_t)(bi+row)*DM + k0 + sw*8;
            size_t ksrc = qbase + (size_t)(bj+row)*DM + k0 + sw*8;
            int ldso = (i*256 + wbase)*8;
            lds16(qh + qsrc, &Qh_s[ldso]);
            lds16(kh + ksrc, &Kh_s[ldso]);
        }
        __syncthreads();

        short8v ah[4], bh4[4];
        #pragma unroll
        for (int f=0; f<4; f++){
            ah[f]  = *reinterpret_cast<short8v*>(&Qh_s[aoff[f]]);
            bh4[f] = *reinterpret_cast<short8v*>(&Kh_s[boff[f]]);
        }
        #pragma unroll
        for (int i=0;i<4;i++)
            #pragma unroll
            for (int j=0;j<4;j++)
                acc[i][j] = __builtin_amdgcn_mfma_f32_16x16x32_f16(
                    __builtin_bit_cast(half8, ah[i]), __builtin_bit_cast(half8, bh4[j]), acc[i][j], 0,0,0);
        __syncthreads();
    }

    float pre[7][4];
    #pragma unroll
    for (int d=0; d<7; d++)
        #pragma unroll
        for (int r=0;r<4;r++) pre[d][r]=0.f;
    #pragma unroll
    for (int i=0;i<4;i++)
        #pragma unroll
        for (int j=0;j<4;j++)
            #pragma unroll
            for (int r=0;r<4;r++)
                pre[i-j+3][r] += acc[i][j][r];
    const int bbase = wm*64 - wn*64 + lg*4 - lr + 127;
    #pragma unroll
    for (int d=0; d<7; d++)
        #pragma unroll
        for (int r=0;r<4;r++)
            atomicAdd(&bins[bbase + 16*(d-3) + r], pre[d][r]);
    __syncthreads();
    float* slot = scr + ((size_t)(b*64 + byt*8 + bxt) << 8);
    for (int i=tid; i<255; i+=256) slot[i] = bins[i];
}

// ---------------- deterministic tile-bin reduction ----------------
__global__ __launch_bounds__(256) void corr_reduce(const float* __restrict__ scr,
                                                   float* __restrict__ mc){
    int b = blockIdx.x;
    int t = blockIdx.y*256 + threadIdx.x;
    float s = 0.f;
    const float* base = scr + ((size_t)b << 14);
    #pragma unroll
    for (int byt=0; byt<8; byt++){
        #pragma unroll
        for (int bxt=0; bxt<8; bxt++){
            int i = (t - 128*(bxt - byt) + 127) & (LL-1);
            if (i < 255) s += base[((byt*8 + bxt) << 8) + i];
        }
    }
    mc[(size_t)b*LL + t] = s * (1.f/256.f);
}

// ---------------- top-16 candidate lags per batch (approx scores) ----------------
__global__ __launch_bounds__(256) void topcand_kernel(const float* __restrict__ mc,
                                                      int* __restrict__ cand){
    int b = blockIdx.x, tid = threadIdx.x;
    __shared__ float sv[LL];
    __shared__ float rv[256];
    __shared__ int ri[256];
    for (int i=tid;i<LL;i+=256) sv[i] = mc[(size_t)b*LL + i];
    __syncthreads();
    for (int it=0; it<TOPC; it++){
        float best = -1e30f; int bi = LL;
        for (int i=tid;i<LL;i+=256){
            float v = sv[i];
            if (v > best || (v == best && i < bi)){ best = v; bi = i; }
        }
        rv[tid]=best; ri[tid]=bi;
        __syncthreads();
        for (int s=128;s>0;s>>=1){
            if (tid < s){
                if (rv[tid+s] > rv[tid] || (rv[tid+s]==rv[tid] && ri[tid+s]<ri[tid])){
                    rv[tid]=rv[tid+s]; ri[tid]=ri[tid+s];
                }
            }
            __syncthreads();
        }
        if (tid==0){ cand[b*TOPC+it]=ri[0]; sv[ri[0]] = -1e30f; }
        __syncthreads();
    }
}

// ---------------- exact rescore of candidates: f32 reconstruct + Kahan, 4-way M-split ----------------
__global__ __launch_bounds__(256) void rescore_k(const ushort* __restrict__ qh,
                                                 const ushort* __restrict__ ql,
                                                 const ushort* __restrict__ kh,
                                                 const ushort* __restrict__ kl,
                                                 const int* __restrict__ cand,
                                                 float* __restrict__ scores4){
    int i = blockIdx.x;
    int b = (i & 7) | (((i >> 3) & 3) << 3);
    int c = i >> 5;
    int chunk = blockIdx.y;
    int t = cand[b*TOPC + c];
    const size_t base = (size_t)b << 18;
    const int off = t << 8;
    const int mbeg = chunk << 16;
    const int mend = mbeg + (1<<16);
    float s = 0.f, comp = 0.f;
    for (int m = mbeg + threadIdx.x*8; m < mend; m += 256*8){
        int mq = (m + off) & ((1<<18)-1);
        short8v kh8 = *reinterpret_cast<const short8v*>(kh + base + m);
        short8v kl8 = *reinterpret_cast<const short8v*>(kl + base + m);
        short8v qh8 = *reinterpret_cast<const short8v*>(qh + base + mq);
        short8v ql8 = *reinterpret_cast<const short8v*>(ql + base + mq);
        float term = 0.f;
        #pragma unroll
        for (int j=0;j<8;j++){
            float kf = h2f((ushort)kh8[j]) + h2f((ushort)kl8[j])*LINV;
            float qf = h2f((ushort)qh8[j]) + h2f((ushort)ql8[j])*LINV;
            term += kf*qf;
        }
        float y = term - comp;
        float tt = s + y;
        comp = (tt - s) - y;
        s = tt;
    }
    for (int o=32;o>0;o>>=1) s += __shfl_down(s, o, 64);
    __shared__ float red[4];
    if ((threadIdx.x & 63)==0) red[threadIdx.x>>6] = s;
    __syncthreads();
    if (threadIdx.x==0)
        scores4[(size_t)(b*TOPC + c)*4 + chunk] = red[0]+red[1]+red[2]+red[3];
}

// ---------------- final top-6 + softmax from exact scores (wave-parallel) ----------------
__global__ __launch_bounds__(64) void finalize_k(const int* __restrict__ cand,
                                                 const float* __restrict__ scores4,
                                                 int* __restrict__ delays,
                                                 float* __restrict__ wts){
    int b = blockIdx.x;
    int lane = threadIdx.x;
    float v = -1e30f;
    int idx = 1<<30;
    if (lane < TOPC){
        size_t s4 = (size_t)(b*TOPC + lane)*4;
        v = (scores4[s4] + scores4[s4+1] + scores4[s4+2] + scores4[s4+3]) * (1.f/256.f);
        idx = cand[b*TOPC + lane];
    }
    float topv[TOPK]; int topi[TOPK];
    #pragma unroll
    for (int k=0;k<TOPK;k++){
        float bv = v; int bi = idx;
        #pragma unroll
        for (int o=8;o>0;o>>=1){
            float ov = __shfl_xor(bv, o, 16);
            int   oi = __shfl_xor(bi, o, 16);
            if (ov > bv || (ov == bv && oi < bi)){ bv = ov; bi = oi; }
        }
        topv[k]=bv; topi[k]=bi;
        if (idx == bi) v = -1e30f;
    }
    if (lane==0){
        float mx = topv[0];
        float e[TOPK], se=0.f;
        #pragma unroll
        for (int k=0;k<TOPK;k++){ e[k]=expf(topv[k]-mx); se+=e[k]; }
        #pragma unroll
        for (int k=0;k<TOPK;k++){
            wts[b*TOPK+k] = e[k]/se;
            delays[b*TOPK+k] = topi[k];
        }
    }
}

// ---------------- attention gather: v f32 -> a split pair ----------------
__global__ __launch_bounds__(256) void attn_gather4(const float4* __restrict__ v,
                                                    const int* __restrict__ delays,
                                                    const float* __restrict__ wts,
                                                    ushort* __restrict__ ah,
                                                    ushort* __restrict__ al){
    int gid = blockIdx.x*256 + threadIdx.x;
    int d4 = gid & 63;
    int bl = gid >> 6;
    int b = bl >> 10, l = bl & (LL-1);
    const int* dl = delays + b*TOPK;
    const float* w = wts + b*TOPK;
    float ax=0.f, ay=0.f, az=0.f, aw=0.f;
    #pragma unroll
    for (int kk=0;kk<TOPK;kk++){
        int ls = (l + dl[kk]) & (LL-1);
        float4 t = v[(size_t)((b<<10)+ls)*64 + d4];
        float wk = w[kk];
        ax += wk*t.x; ay += wk*t.y; az += wk*t.z; aw += wk*t.w;
    }
    storep4(ah, al, gid, make_float4(ax, ay, az, aw));
}

// ---------------- decomp: (pair + f32) - movmean5 -> pair ----------------
__global__ __launch_bounds__(256) void add_decomp_pf_p(const ushort* __restrict__ xah,
                                                       const ushort* __restrict__ xal,
                                                       const float4* __restrict__ xb,
                                                       ushort* __restrict__ oh,
                                                       ushort* __restrict__ ol){
    int d4 = threadIdx.x & 63;
    int rg = threadIdx.x >> 6;
    int b = blockIdx.x;
    int l0 = blockIdx.y*128 + rg*32;
    float4 win[5];
    #pragma unroll
    for (int i=0;i<4;i++){
        int g = l0 - 2 + i;
        g = g < 0 ? 0 : g;
        size_t idx = (size_t)((b<<10) + g)*64 + d4;
        float4 A = loadp4(xah, xal, idx), Bv = xb[idx];
        win[i] = make_float4(A.x+Bv.x, A.y+Bv.y, A.z+Bv.z, A.w+Bv.w);
    }
    for (int i=0;i<32;i++){
        int g = l0 + 2 + i;
        g = g > LL-1 ? LL-1 : g;
        size_t idx = (size_t)((b<<10) + g)*64 + d4;
        float4 A = loadp4(xah, xal, idx), Bv = xb[idx];
        win[4] = make_float4(A.x+Bv.x, A.y+Bv.y, A.z+Bv.z, A.w+Bv.w);
        float4 o;
        o.x = win[2].x - (win[0].x+win[1].x+win[2].x+win[3].x+win[4].x)*0.2f;
        o.y = win[2].y - (win[0].y+win[1].y+win[2].y+win[3].y+win[4].y)*0.2f;
        o.z = win[2].z - (win[0].z+win[1].z+win[2].z+win[3].z+win[4].z)*0.2f;
        o.w = win[2].w - (win[0].w+win[1].w+win[2].w+win[3].w+win[4].w)*0.2f;
        storep4(oh, ol, (size_t)((b<<10) + l0 + i)*64 + d4, o);
        win[0]=win[1]; win[1]=win[2]; win[2]=win[3]; win[3]=win[4];
    }
}

// decomp 3-input: (pair + f32 + f32) - movmean5 -> pair
__global__ __launch_bounds__(256) void add_decomp3_pff_p(const ushort* __restrict__ xah,
                                                         const ushort* __restrict__ xal,
                                                         const float4* __restrict__ xb,
                                                         const float4* __restrict__ xc,
                                                         ushort* __restrict__ oh,
                                                         ushort* __restrict__ ol){
    int d4 = threadIdx.x & 63;
    int rg = threadIdx.x >> 6;
    int b = blockIdx.x;
    int l0 = blockIdx.y*128 + rg*32;
    float4 win[5];
    #pragma unroll
    for (int i=0;i<4;i++){
        int g = l0 - 2 + i;
        g = g < 0 ? 0 : g;
        size_t idx = (size_t)((b<<10) + g)*64 + d4;
        float4 A = loadp4(xah, xal, idx), Bv = xb[idx], Cc = xc[idx];
        win[i] = make_float4(A.x+Bv.x+Cc.x, A.y+Bv.y+Cc.y, A.z+Bv.z+Cc.z, A.w+Bv.w+Cc.w);
    }
    for (int i=0;i<32;i++){
        int g = l0 + 2 + i;
        g = g > LL-1 ? LL-1 : g;
        size_t idx = (size_t)((b<<10) + g)*64 + d4;
        float4 A = loadp4(xah, xal, idx), Bv = xb[idx], Cc = xc[idx];
        win[4] = make_float4(A.x+Bv.x+Cc.x, A.y+Bv.y+Cc.y, A.z+Bv.z+Cc.z, A.w+Bv.w+Cc.w);
        float4 o;
        o.x = win[2].x - (win[0].x+win[1].x+win[2].x+win[3].x+win[4].x)*0.2f;
        o.y = win[2].y - (win[0].y+win[1].y+win[2].y+win[3].y+win[4].y)*0.2f;
        o.z = win[2].z - (win[0].z+win[1].z+win[2].z+win[3].z+win[4].z)*0.2f;
        o.w = win[2].w - (win[0].w+win[1].w+win[2].w+win[3].w+win[4].w)*0.2f;
        storep4(oh, ol, (size_t)((b<<10) + l0 + i)*64 + d4, o);
        win[0]=win[1]; win[1]=win[2]; win[2]=win[3]; win[3]=win[4];
    }
}

// ---------------- layernorm over d per (b,l), pair input ----------------
__global__ __launch_bounds__(256) void ln_kernel(const ushort* __restrict__ xh_,
                                                 const ushort* __restrict__ xl_,
                                                 const float* __restrict__ nw,
                                                 const float* __restrict__ nb,
                                                 float* __restrict__ xh){
    int bl = blockIdx.x, d = threadIdx.x;
    size_t i = (size_t)bl*DM + d;
    float val = h2f(xh_[i]) + h2f(xl_[i])*LINV;
    __shared__ float red[4];
    float v = val;
    for (int o=32;o>0;o>>=1) v += __shfl_down(v, o, 64);
    if ((d&63)==0) red[d>>6] = v;
    __syncthreads();
    float mu = (red[0]+red[1]+red[2]+red[3])*(1.f/256.f);
    __syncthreads();
    float diff = val - mu;
    v = diff*diff;
    for (int o=32;o>0;o>>=1) v += __shfl_down(v, o, 64);
    if ((d&63)==0) red[d>>6] = v;
    __syncthreads();
    float var = (red[0]+red[1]+red[2]+red[3])*(1.f/256.f);
    xh[i] = diff*rsqrtf(var+1e-5f)*nw[d] + nb[d];
}

// ---------------- column sums over l ----------------
__global__ __launch_bounds__(256) void colsum_kernel(const float* __restrict__ xh,
                                                     float* __restrict__ colsum){
    int b = blockIdx.x, chunk = blockIdx.y, d = threadIdx.x;
    float s = 0.f;
    for (int l = chunk*128; l < (chunk+1)*128; l++)
        s += xh[((size_t)b*LL + l)*DM + d];
    atomicAdd(&colsum[b*DM + d], s);
}

// ---------------- g = gelu(xh - colmean) ----------------
__global__ __launch_bounds__(256) void gelu_sub_kernel(const float* __restrict__ xh,
                                                       const float* __restrict__ colsum,
                                                       float* __restrict__ g){
    int bl = blockIdx.x, d = threadIdx.x;
    int b = bl / LL;
    float v = xh[(size_t)bl*DM + d] - colsum[b*DM + d]*(1.f/1024.f);
    g[(size_t)bl*DM + d] = gelu_f(v);
}

// ---------------- final projection ----------------
__global__ __launch_bounds__(256) void proj_kernel(const float* __restrict__ g,
                                                   const float* __restrict__ pw,
                                                   const float* __restrict__ pb,
                                                   float* __restrict__ out){
    int b = blockIdx.x, c = blockIdx.y, ch = blockIdx.z;
    int tid = threadIdx.x;
    const size_t F = (size_t)LL*DM;
    size_t base = ch*(F/16);
    float s = 0.f;
    for (size_t i = tid; i < F/16; i += 256)
        s += g[(size_t)b*F + base + i] * pw[(size_t)c*F + base + i];
    for (int o=32;o>0;o>>=1) s += __shfl_down(s, o, 64);
    __shared__ float red[4];
    if ((tid&63)==0) red[tid>>6] = s;
    __syncthreads();
    if (tid==0){
        float tot = red[0]+red[1]+red[2]+red[3];
        if (ch==0) tot += pb[c];
        atomicAdd(&out[b*3 + c], tot);
    }
}

extern "C" void kernel_launch(void* const* d_in, const int* in_sizes, int n_in,
                              void* d_out, int out_size, void* d_ws, size_t ws_size,
                              hipStream_t stream) {
    const float* x_enc   = (const float*)d_in[0];
    const float* token_w = (const float*)d_in[1];
    const float* qw = (const float*)d_in[2];
    const float* qb = (const float*)d_in[3];
    const float* kw = (const float*)d_in[4];
    const float* kb = (const float*)d_in[5];
    const float* vw = (const float*)d_in[6];
    const float* vb = (const float*)d_in[7];
    const float* ow = (const float*)d_in[8];
    const float* ob = (const float*)d_in[9];
    const float* c1w = (const float*)d_in[10];
    const float* c2w = (const float*)d_in[11];
    const float* norm_w = (const float*)d_in[12];
    const float* norm_b = (const float*)d_in[13];
    const float* proj_w = (const float*)d_in[14];
    const float* proj_b = (const float*)d_in[15];
    float* outp = (float*)d_out;

    const size_t NTOK = (size_t)BB*LL*DM;        // 8388608
    float* ws = (float*)d_ws;
    float* buf0 = ws;            // x pair / y pair
    float* buf1 = ws + NTOK;     // q pair / a pair / x1 pair / ln-out f32
    float* buf2 = ws + 2*NTOK;   // k pair / o f32 / y2 f32 / gelu f32
    ushort* wu = (ushort*)(ws + 3*NTOK);
    const size_t WSM = (size_t)NLAYERS*DM*DM;    // 196608
    const size_t WSF = (size_t)NLAYERS*DFF*DM;   // 786432
    ushort* qkwh = wu;             ushort* qkwl = qkwh + 2*WSM;
    ushort* vwh  = qkwl + 2*WSM;   ushort* vwl  = vwh + WSM;
    ushort* owh  = vwl + WSM;      ushort* owl  = owh + WSM;
    ushort* c1wh = owl + WSM;      ushort* c1wl = c1wh + WSF;
    ushort* c2wh = c1wl + WSF;     ushort* c2wl = c2wh + WSF;
    float* after_w = ws + 3*NTOK + 2359296;
    float* qkbias = after_w;                       // 3*512
    float* mc     = qkbias + (size_t)NLAYERS*512;  // 32768
    float* colsum = mc + (size_t)BB*LL;            // 8192
    int*   delays = (int*)(colsum + BB*DM);        // 192
    float* wts    = (float*)(delays + BB*TOPK);    // 192
    int*   cand   = (int*)(wts + BB*TOPK);         // 512
    float* scores4 = (float*)(cand + BB*TOPC);     // 2048
    float* twT    = scores4 + BB*TOPC*4;           // 16128
    float* scr    = twT + 63*256;                  // 524288
    float* buf3   = scr + 524288;                  // v f32 / FFN2 partial f32

    const size_t needed_floats = 3*NTOK + 2359296 + (size_t)NLAYERS*512 + (size_t)BB*LL
                               + (size_t)BB*DM + (size_t)BB*TOPK*2 + (size_t)BB*TOPC
                               + (size_t)BB*TOPC*4 + 63*256 + 524288 + NTOK;
    const bool zs = (ws_size >= needed_floats*sizeof(float));

    hipMemsetAsync(d_out, 0, 96*sizeof(float), stream);

    {
        int n1 = NLAYERS*DM*DM;
        int n2 = NLAYERS*DFF*DM;
        split_w_strided<<<(n1+255)/256, 256, 0, stream>>>(qw, qkwh, qkwl, n1, 65536, 131072, 0);
        split_w_strided<<<(n1+255)/256, 256, 0, stream>>>(kw, qkwh, qkwl, n1, 65536, 131072, 65536);
        cat_bias_k<<<(NLAYERS*512+255)/256, 256, 0, stream>>>(qb, kb, qkbias, NLAYERS*512);
        split_w_k<<<(n1+255)/256, 256, 0, stream>>>(vw, vwh, vwl, n1);
        split_w_k<<<(n1+255)/256, 256, 0, stream>>>(ow, owh, owl, n1);
        split_w_k<<<(n2+255)/256, 256, 0, stream>>>(c1w, c1wh, c1wl, n2);
        split_w_k<<<(n2+255)/256, 256, 0, stream>>>(c2w, c2wh, c2wl, n2);
        transpose_tw<<<(256*63+255)/256, 256, 0, stream>>>(token_w, twT);
    }

    // x pair in buf0
    ushort* xh_p = (ushort*)buf0;  ushort* xl_p = xh_p + NTOK;
    token_embed_k<<<dim3(BB, LL/32), 256, 0, stream>>>(x_enc, twT, xh_p, xl_p);

    const int M = BB*LL;  // 32768
    const int FFNC = 8192;

    for (int l=0; l<NLAYERS; l++){
        ushort* qkwh_l = qkwh + (size_t)l*512*DM;  ushort* qkwl_l = qkwl + (size_t)l*512*DM;
        ushort* vwh_l = vwh + (size_t)l*DM*DM;     ushort* vwl_l = vwl + (size_t)l*DM*DM;
        ushort* owh_l = owh + (size_t)l*DM*DM;     ushort* owl_l = owl + (size_t)l*DM*DM;
        ushort* c1wh_l = c1wh + (size_t)l*DFF*DM;  ushort* c1wl_l = c1wl + (size_t)l*DFF*DM;
        ushort* c2wh_l = c2wh + (size_t)l*DM*DFF;  ushort* c2wl_l = c2wl + (size_t)l*DM*DFF;
        const float* qkb_l = qkbias + (size_t)l*512;
        const float* vb_l = vb + (size_t)l*DM;
        const float* ob_l = ob + (size_t)l*DM;

        // fused q+k -> buf1 pair (q), buf2 pair (k)
        ushort* qh_p = (ushort*)buf1;  ushort* ql_p = qh_p + NTOK;
        ushort* kh_p = (ushort*)buf2;  ushort* kl_p = kh_p + NTOK;
        gemm_mfma_split<true,false,3,false><<<(M/128)*(512/64), 256, 0, stream>>>(
            xh_p, xl_p, qkwh_l, qkwl_l, qkb_l, qh_p, ql_p, kh_p, kl_p, M, 512, DM);

        // approx corr -> reduce -> candidates -> exact rescore -> top-6
        corr_mfma<<<2048, 256, 0, stream>>>(qh_p, kh_p, scr);
        corr_reduce<<<dim3(BB, 4), 256, 0, stream>>>(scr, mc);
        topcand_kernel<<<BB, 256, 0, stream>>>(mc, cand);
        rescore_k<<<dim3(BB*TOPC, 4), 256, 0, stream>>>(qh_p, ql_p, kh_p, kl_p, cand, scores4);
        finalize_k<<<BB, 64, 0, stream>>>(cand, scores4, delays, wts);

        // v -> buf3 (f32), a pair -> buf1 (q dead), o f32 -> buf2 (k dead)
        gemm_mfma_split<true,false,0,false><<<(M/128)*(DM/64), 256, 0, stream>>>(
            xh_p, xl_p, vwh_l, vwl_l, vb_l, buf3, nullptr, nullptr, nullptr, M, DM, DM);
        ushort* ah_p = (ushort*)buf1;  ushort* al_p = ah_p + NTOK;
        attn_gather4<<<(BB*LL*64)/256, 256, 0, stream>>>(
            (const float4*)buf3, delays, wts, ah_p, al_p);
        gemm_mfma_split<true,false,0,false><<<(M/128)*(DM/64), 256, 0, stream>>>(
            ah_p, al_p, owh_l, owl_l, ob_l, buf2, nullptr, nullptr, nullptr, M, DM, DM);

        // x1 pair = (x + o) - movmean -> buf1 (a dead)
        ushort* x1h_p = (ushort*)buf1;  ushort* x1l_p = x1h_p + NTOK;
        add_decomp_pf_p<<<dim3(BB, LL/128), 256, 0, stream>>>(
            xh_p, xl_p, (const float4*)buf2, x1h_p, x1l_p);

        // FFN chunked: y pair in buf0 (x dead); y2 f32 -> buf2 (+ buf3 partial when zs)
        ushort* yh_p = (ushort*)buf0;
        ushort* yl_p = yh_p + (size_t)FFNC*DFF;
        for (int c0 = 0; c0 < M; c0 += FFNC){
            gemm_mfma_split<false,true,2,false><<<(FFNC/128)*(DFF/64), 256, 0, stream>>>(
                x1h_p + (size_t)c0*DM, x1l_p + (size_t)c0*DM, c1wh_l, c1wl_l, nullptr,
                yh_p, yl_p, nullptr, nullptr, FFNC, DFF, DM);
            if (zs){
                gemm_mfma_split<false,false,0,true><<<dim3((FFNC/128)*(DM/64), 2), 256, 0, stream>>>(
                    yh_p, yl_p, c2wh_l, c2wl_l, nullptr,
                    buf2 + (size_t)c0*DM, buf3 + (size_t)c0*DM, nullptr, nullptr, FFNC, DM, DFF);
            } else {
                gemm_mfma_split<false,false,0,false><<<(FFNC/128)*(DM/64), 256, 0, stream>>>(
                    yh_p, yl_p, c2wh_l, c2wl_l, nullptr,
                    buf2 + (size_t)c0*DM, nullptr, nullptr, nullptr, FFNC, DM, DFF);
            }
        }

        // x pair = (x1 + y2 [+partial]) - movmean -> buf0 (y dead)
        if (zs)
            add_decomp3_pff_p<<<dim3(BB, LL/128), 256, 0, stream>>>(
                x1h_p, x1l_p, (const float4*)buf2, (const float4*)buf3, xh_p, xl_p);
        else
            add_decomp_pf_p<<<dim3(BB, LL/128), 256, 0, stream>>>(
                x1h_p, x1l_p, (const float4*)buf2, xh_p, xl_p);
    }

    // final layernorm (pair in) -> buf1 f32
    ln_kernel<<<BB*LL, 256, 0, stream>>>(xh_p, xl_p, norm_w, norm_b, buf1);
    hipMemsetAsync(colsum, 0, (size_t)BB*DM*sizeof(float), stream);
    colsum_kernel<<<dim3(BB, 8), 256, 0, stream>>>(buf1, colsum);
    gelu_sub_kernel<<<BB*LL, 256, 0, stream>>>(buf1, colsum, buf2);
    proj_kernel<<<dim3(BB, 3, 16), 256, 0, stream>>>(buf2, proj_w, proj_b, outp);
}

// Round 17
// 1836.568 us; speedup vs baseline: 1.0026x; 1.0026x over previous
//
#include <hip/hip_runtime.h>
#include <hip/hip_bf16.h>
#include <math.h>

// Problem constants
#define BB 32
#define LL 1024
#define C_IN 21
#define DM 256
#define DFF 1024
#define NLAYERS 3
#define TOPK 6
#define TOPC 16
#define LSCALE 4096.0f
#define LINV (1.0f/4096.0f)

typedef __attribute__((ext_vector_type(8))) short short8v;
typedef __attribute__((ext_vector_type(8))) _Float16 half8;
typedef __attribute__((ext_vector_type(4))) float f32x4;

__device__ __forceinline__ float gelu_f(float v){
    return 0.5f * v * (1.0f + erff(v * 0.7071067811865476f));
}
__device__ __forceinline__ ushort f2h_bits(float f){
    _Float16 h = (_Float16)f;
    return __builtin_bit_cast(ushort, h);
}
__device__ __forceinline__ float h2f(ushort u){
    return (float)__builtin_bit_cast(_Float16, u);
}
// direct global->LDS 16B copy (wave-uniform LDS base + lane*16)
__device__ __forceinline__ void lds16(const ushort* g, ushort* l){
    __builtin_amdgcn_global_load_lds(
        (const __attribute__((address_space(1))) void*)g,
        (__attribute__((address_space(3))) void*)l, 16, 0, 0);
}
// split-pair helpers (4 elements)
__device__ __forceinline__ float4 loadp4(const ushort* __restrict__ h, const ushort* __restrict__ l, size_t i4){
    ushort4 hv = *reinterpret_cast<const ushort4*>(h + 4*i4);
    ushort4 lv = *reinterpret_cast<const ushort4*>(l + 4*i4);
    return make_float4(h2f(hv.x)+h2f(lv.x)*LINV, h2f(hv.y)+h2f(lv.y)*LINV,
                       h2f(hv.z)+h2f(lv.z)*LINV, h2f(hv.w)+h2f(lv.w)*LINV);
}
__device__ __forceinline__ void storep4(ushort* __restrict__ h, ushort* __restrict__ l, size_t i4, float4 v){
    ushort4 hv, lv;
    _Float16 a;
    a=(_Float16)v.x; hv.x=__builtin_bit_cast(ushort,a); lv.x=f2h_bits((v.x-(float)a)*LSCALE);
    a=(_Float16)v.y; hv.y=__builtin_bit_cast(ushort,a); lv.y=f2h_bits((v.y-(float)a)*LSCALE);
    a=(_Float16)v.z; hv.z=__builtin_bit_cast(ushort,a); lv.z=f2h_bits((v.z-(float)a)*LSCALE);
    a=(_Float16)v.w; hv.w=__builtin_bit_cast(ushort,a); lv.w=f2h_bits((v.w-(float)a)*LSCALE);
    *reinterpret_cast<ushort4*>(h + 4*i4) = hv;
    *reinterpret_cast<ushort4*>(l + 4*i4) = lv;
}

// ---------------- weight conversion: f16 hi + 4096*lo ----------------
__global__ __launch_bounds__(256) void split_w_k(const float* __restrict__ src,
                                                 ushort* __restrict__ h, ushort* __restrict__ l, int n){
    int i = blockIdx.x*256 + threadIdx.x;
    if (i < n){
        float f = src[i];
        _Float16 hh = (_Float16)f;
        h[i] = __builtin_bit_cast(ushort, hh);
        l[i] = f2h_bits((f - (float)hh) * LSCALE);
    }
}
__global__ __launch_bounds__(256) void split_w_strided(const float* __restrict__ src,
                                                       ushort* __restrict__ h, ushort* __restrict__ l,
                                                       int n, int src_ls, int dst_ls, int dst_off){
    int i = blockIdx.x*256 + threadIdx.x;
    if (i < n){
        int layer = i / src_ls, r = i % src_ls;
        float f = src[i];
        _Float16 hh = (_Float16)f;
        size_t d = (size_t)layer*dst_ls + dst_off + r;
        h[d] = __builtin_bit_cast(ushort, hh);
        l[d] = f2h_bits((f - (float)hh) * LSCALE);
    }
}
__global__ __launch_bounds__(256) void cat_bias3_k(const float* __restrict__ b1,
                                                   const float* __restrict__ b2,
                                                   const float* __restrict__ b3,
                                                   float* __restrict__ out, int n){ // n = 3*768
    int i = blockIdx.x*256 + threadIdx.x;
    if (i < n){
        int layer = i / 768, c = i % 768;
        out[i] = (c < 256) ? b1[layer*256 + c]
               : (c < 512) ? b2[layer*256 + c - 256]
                           : b3[layer*256 + c - 512];
    }
}
// transpose token weight [256][63] -> [63][256]
__global__ __launch_bounds__(256) void transpose_tw(const float* __restrict__ src,
                                                    float* __restrict__ dst){
    int i = blockIdx.x*256 + threadIdx.x;
    if (i < 256*63){
        int d = i / 63, k = i % 63;
        dst[k*256 + d] = src[i];
    }
}

// ---------------- token embedding: circular conv1d k=3, split-pair output ----------------
__global__ __launch_bounds__(256) void token_embed_k(const float* __restrict__ x,
                                                     const float* __restrict__ wT,
                                                     ushort* __restrict__ oh,
                                                     ushort* __restrict__ ol){
    int b = blockIdx.x, l0 = blockIdx.y*32;
    int d = threadIdx.x;
    __shared__ float xs[34][C_IN];
    for (int i = threadIdx.x; i < 34*C_IN; i += 256){
        int r = i / C_IN, c = i % C_IN;
        int g = (l0 - 1 + r + LL) & (LL-1);
        xs[r][c] = x[(size_t)b*LL*C_IN + (size_t)g*C_IN + c];
    }
    float w[63];
    #pragma unroll
    for (int k=0;k<63;k++) w[k] = wT[k*256 + d];
    __syncthreads();
    for (int i=0;i<32;i++){
        float acc = 0.f;
        #pragma unroll
        for (int c=0;c<C_IN;c++){
            acc += xs[i][c]   * w[c*3+0];
            acc += xs[i+1][c] * w[c*3+1];
            acc += xs[i+2][c] * w[c*3+2];
        }
        size_t idx = ((size_t)b*LL + l0+i)*DM + d;
        _Float16 hh = (_Float16)acc;
        oh[idx] = __builtin_bit_cast(ushort, hh);
        ol[idx] = f2h_bits((acc - (float)hh) * LSCALE);
    }
}

// =================== split-f16 MFMA GEMM, block 128x64, global_load_lds staging ===================
// OMODE: 0 = f32 out (Cv), 2 = split pair out (Cv,C2v),
//        4 = fused qkv: col<256 -> q pair (Cv,C2v), col<512 -> k pair (C3v,C4v), else v f32 (C5v); stride 256
template<bool BIAS, bool GELU, int OMODE, bool ZSPLIT>
__global__ __launch_bounds__(256) void gemm_mfma_split(const ushort* __restrict__ Ah_g,
                                                       const ushort* __restrict__ Al_g,
                                                       const ushort* __restrict__ Wh,
                                                       const ushort* __restrict__ Wl,
                                                       const float* __restrict__ bias,
                                                       void* __restrict__ Cv,
                                                       void* __restrict__ C2v,
                                                       void* __restrict__ C3v,
                                                       void* __restrict__ C4v,
                                                       void* __restrict__ C5v,
                                                       int M, int N, int K){
    __shared__ __align__(16) ushort Ah_s[128*32];
    __shared__ __align__(16) ushort Al_s[128*32];
    __shared__ __align__(16) ushort Wh_s[64*32];
    __shared__ __align__(16) ushort Wl_s[64*32];

    const int tid = threadIdx.x;
    const int MB = M >> 7;
    const int bx = blockIdx.x % MB, by = blockIdx.x / MB;
    const int bm = bx << 7, bn = by << 6;

    const int lane = tid & 63;
    const int wid  = tid >> 6;
    const int wm = wid >> 1, wn = wid & 1;
    const int lr = lane & 15, lg = lane >> 4;

    int aoff[4], boff[2];
    #pragma unroll
    for (int f=0; f<4; f++){
        int ar = wm*64 + f*16 + lr;
        aoff[f] = ar*32 + (lg ^ ((ar>>1)&3))*8;
    }
    #pragma unroll
    for (int g=0; g<2; g++){
        int br = wn*32 + g*16 + lr;
        boff[g] = br*32 + (lg ^ ((br>>1)&3))*8;
    }

    f32x4 acc[4][2], accX[4][2];
    #pragma unroll
    for (int i=0;i<4;i++)
        #pragma unroll
        for (int j=0;j<2;j++){
            acc[i][j]  = (f32x4){0.f,0.f,0.f,0.f};
            accX[i][j] = (f32x4){0.f,0.f,0.f,0.f};
        }

    const int kbeg = ZSPLIT ? (int)blockIdx.y * (K>>1) : 0;
    const int kend = ZSPLIT ? kbeg + (K>>1) : K;
    const int wbase = (tid & 192);   // wave-uniform

    for (int k0=kbeg; k0<kend; k0+=32){
        #pragma unroll
        for (int i=0;i<2;i++){
            int c = i*256 + tid;
            int row = c >> 2, ko = c & 3;
            int sw = ko ^ ((row>>1)&3);
            size_t src = (size_t)(bm+row)*K + k0 + sw*8;
            int ldso = (i*256 + wbase)*8;
            lds16(Ah_g + src, &Ah_s[ldso]);
            lds16(Al_g + src, &Al_s[ldso]);
        }
        {
            int row = tid >> 2, ko = tid & 3;
            int sw = ko ^ ((row>>1)&3);
            size_t src = (size_t)(bn+row)*K + k0 + sw*8;
            int ldso = wbase*8;
            lds16(Wh + src, &Wh_s[ldso]);
            lds16(Wl + src, &Wl_s[ldso]);
        }
        __syncthreads();

        short8v af[4], al[4], bf_[2], bl[2];
        #pragma unroll
        for (int f=0; f<4; f++){
            af[f] = *reinterpret_cast<short8v*>(&Ah_s[aoff[f]]);
            al[f] = *reinterpret_cast<short8v*>(&Al_s[aoff[f]]);
        }
        #pragma unroll
        for (int g=0; g<2; g++){
            bf_[g] = *reinterpret_cast<short8v*>(&Wh_s[boff[g]]);
            bl[g]  = *reinterpret_cast<short8v*>(&Wl_s[boff[g]]);
        }
        #pragma unroll
        for (int i=0;i<4;i++){
            #pragma unroll
            for (int j=0;j<2;j++){
                acc[i][j] = __builtin_amdgcn_mfma_f32_16x16x32_f16(
                    __builtin_bit_cast(half8, af[i]), __builtin_bit_cast(half8, bf_[j]), acc[i][j], 0,0,0);
                accX[i][j] = __builtin_amdgcn_mfma_f32_16x16x32_f16(
                    __builtin_bit_cast(half8, af[i]), __builtin_bit_cast(half8, bl[j]), accX[i][j], 0,0,0);
                accX[i][j] = __builtin_amdgcn_mfma_f32_16x16x32_f16(
                    __builtin_bit_cast(half8, al[i]), __builtin_bit_cast(half8, bf_[j]), accX[i][j], 0,0,0);
            }
        }
        __syncthreads();
    }

    // ---- epilogue ----
    float* Cout0 = (float*)((ZSPLIT && blockIdx.y) ? C2v : Cv);
    const int crow0 = bm + wm*64, ccol0 = bn + wn*32;
    #pragma unroll
    for (int i=0;i<4;i++){
        #pragma unroll
        for (int j=0;j<2;j++){
            int row0 = crow0 + i*16 + lg*4;
            int col  = ccol0 + j*16 + lr;
            float bv = (BIAS && (!ZSPLIT || blockIdx.y==0)) ? bias[col] : 0.f;
            #pragma unroll
            for (int r=0;r<4;r++){
                float v = acc[i][j][r] + accX[i][j][r]*LINV + bv;
                if (GELU) v = gelu_f(v);
                if (OMODE == 0){
                    Cout0[(size_t)(row0+r)*N + col] = v;
                } else if (OMODE == 2){
                    size_t idx = (size_t)(row0+r)*N + col;
                    _Float16 hh = (_Float16)v;
                    ((ushort*)Cv)[idx]  = __builtin_bit_cast(ushort, hh);
                    ((ushort*)C2v)[idx] = f2h_bits((v - (float)hh) * LSCALE);
                } else { // OMODE 4: fused qkv, out stride 256
                    if (col < 512){
                        _Float16 hh = (_Float16)v;
                        ushort hb = __builtin_bit_cast(ushort, hh);
                        ushort lb = f2h_bits((v - (float)hh) * LSCALE);
                        if (col < 256){
                            size_t idx = (size_t)(row0+r)*256 + col;
                            ((ushort*)Cv)[idx]  = hb;
                            ((ushort*)C2v)[idx] = lb;
                        } else {
                            size_t idx = (size_t)(row0+r)*256 + (col-256);
                            ((ushort*)C3v)[idx] = hb;
                            ((ushort*)C4v)[idx] = lb;
                        }
                    } else {
                        ((float*)C5v)[(size_t)(row0+r)*256 + (col-512)] = v;
                    }
                }
            }
        }
    }
}

// =================== corr (APPROX, hi-plane only): 128x128 Gram tile, global_load_lds staging ===================
__global__ __launch_bounds__(256) void corr_mfma(const ushort* __restrict__ qh,
                                                 const ushort* __restrict__ kh,
                                                 float* __restrict__ scr){
    __shared__ __align__(16) ushort Qh_s[128*32];
    __shared__ __align__(16) ushort Kh_s[128*32];
    __shared__ float bins[255];

    const int tid = threadIdx.x;
    int flat = blockIdx.x;
    flat = (flat & 7) * 256 + (flat >> 3);   // XCD-aware swizzle
    const int bxt = flat & 7;
    const int byt = (flat >> 3) & 7;
    const int b   = flat >> 6;
    const int bi = bxt * 128, bj = byt * 128;

    for (int i=tid; i<255; i+=256) bins[i] = 0.f;

    const int lane = tid & 63;
    const int wid  = tid >> 6;
    const int wm = wid >> 1, wn = wid & 1;
    const int lr = lane & 15, lg = lane >> 4;

    int aoff[4], boff[4];
    #pragma unroll
    for (int f=0; f<4; f++){
        int ar = wm*64 + f*16 + lr;
        aoff[f] = ar*32 + (lg ^ ((ar>>1)&3))*8;
        int br = wn*64 + f*16 + lr;
        boff[f] = br*32 + (lg ^ ((br>>1)&3))*8;
    }

    f32x4 acc[4][4];
    #pragma unroll
    for (int i=0;i<4;i++)
        #pragma unroll
        for (int j=0;j<4;j++)
            acc[i][j] = (f32x4){0.f,0.f,0.f,0.f};

    const size_t qbase = (size_t)b*LL*DM;
    const int wbase = (tid & 192);

    for (int k0=0; k0<DM; k0+=32){
        #pragma unroll
        for (int i=0;i<2;i++){
            int c = i*256 + tid;
            int row = c >> 2, ko = c & 3;
            int sw = ko ^ ((row>>1)&3);
            size_t qsrc = qbase + (size_t)(bi+row)*DM + k0 + sw*8;
            size_t ksrc = qbase + (size_t)(bj+row)*DM + k0 + sw*8;
            int ldso = (i*256 + wbase)*8;
            lds16(qh + qsrc, &Qh_s[ldso]);
            lds16(kh + ksrc, &Kh_s[ldso]);
        }
        __syncthreads();

        short8v ah[4], bh4[4];
        #pragma unroll
        for (int f=0; f<4; f++){
            ah[f]  = *reinterpret_cast<short8v*>(&Qh_s[aoff[f]]);
            bh4[f] = *reinterpret_cast<short8v*>(&Kh_s[boff[f]]);
        }
        #pragma unroll
        for (int i=0;i<4;i++)
            #pragma unroll
            for (int j=0;j<4;j++)
                acc[i][j] = __builtin_amdgcn_mfma_f32_16x16x32_f16(
                    __builtin_bit_cast(half8, ah[i]), __builtin_bit_cast(half8, bh4[j]), acc[i][j], 0,0,0);
        __syncthreads();
    }

    float pre[7][4];
    #pragma unroll
    for (int d=0; d<7; d++)
        #pragma unroll
        for (int r=0;r<4;r++) pre[d][r]=0.f;
    #pragma unroll
    for (int i=0;i<4;i++)
        #pragma unroll
        for (int j=0;j<4;j++)
            #pragma unroll
            for (int r=0;r<4;r++)
                pre[i-j+3][r] += acc[i][j][r];
    const int bbase = wm*64 - wn*64 + lg*4 - lr + 127;
    #pragma unroll
    for (int d=0; d<7; d++)
        #pragma unroll
        for (int r=0;r<4;r++)
            atomicAdd(&bins[bbase + 16*(d-3) + r], pre[d][r]);
    __syncthreads();
    float* slot = scr + ((size_t)(b*64 + byt*8 + bxt) << 8);
    for (int i=tid; i<255; i+=256) slot[i] = bins[i];
}

// ---------------- fused: deterministic tile-bin reduce + top-16 candidates ----------------
__global__ __launch_bounds__(256) void corr_sel(const float* __restrict__ scr,
                                                int* __restrict__ cand){
    int b = blockIdx.x, tid = threadIdx.x;
    __shared__ float sv[LL];
    __shared__ float rv[256];
    __shared__ int ri[256];
    const float* base = scr + ((size_t)b << 14);
    for (int t = tid; t < LL; t += 256){
        float s = 0.f;
        #pragma unroll
        for (int byt=0; byt<8; byt++){
            #pragma unroll
            for (int bxt=0; bxt<8; bxt++){
                int i = (t - 128*(bxt - byt) + 127) & (LL-1);
                if (i < 255) s += base[((byt*8 + bxt) << 8) + i];
            }
        }
        sv[t] = s * (1.f/256.f);
    }
    __syncthreads();
    for (int it=0; it<TOPC; it++){
        float best = -1e30f; int bi = LL;
        for (int i=tid;i<LL;i+=256){
            float v = sv[i];
            if (v > best || (v == best && i < bi)){ best = v; bi = i; }
        }
        rv[tid]=best; ri[tid]=bi;
        __syncthreads();
        for (int s=128;s>0;s>>=1){
            if (tid < s){
                if (rv[tid+s] > rv[tid] || (rv[tid+s]==rv[tid] && ri[tid+s]<ri[tid])){
                    rv[tid]=rv[tid+s]; ri[tid]=ri[tid+s];
                }
            }
            __syncthreads();
        }
        if (tid==0){ cand[b*TOPC+it]=ri[0]; sv[ri[0]] = -1e30f; }
        __syncthreads();
    }
}

// ---------------- exact rescore of candidates: f32 reconstruct + Kahan, 4-way M-split ----------------
__global__ __launch_bounds__(256) void rescore_k(const ushort* __restrict__ qh,
                                                 const ushort* __restrict__ ql,
                                                 const ushort* __restrict__ kh,
                                                 const ushort* __restrict__ kl,
                                                 const int* __restrict__ cand,
                                                 float* __restrict__ scores4){
    int i = blockIdx.x;
    int b = (i & 7) | (((i >> 3) & 3) << 3);
    int c = i >> 5;
    int chunk = blockIdx.y;
    int t = cand[b*TOPC + c];
    const size_t base = (size_t)b << 18;
    const int off = t << 8;
    const int mbeg = chunk << 16;
    const int mend = mbeg + (1<<16);
    float s = 0.f, comp = 0.f;
    for (int m = mbeg + threadIdx.x*8; m < mend; m += 256*8){
        int mq = (m + off) & ((1<<18)-1);
        short8v kh8 = *reinterpret_cast<const short8v*>(kh + base + m);
        short8v kl8 = *reinterpret_cast<const short8v*>(kl + base + m);
        short8v qh8 = *reinterpret_cast<const short8v*>(qh + base + mq);
        short8v ql8 = *reinterpret_cast<const short8v*>(ql + base + mq);
        float term = 0.f;
        #pragma unroll
        for (int j=0;j<8;j++){
            float kf = h2f((ushort)kh8[j]) + h2f((ushort)kl8[j])*LINV;
            float qf = h2f((ushort)qh8[j]) + h2f((ushort)ql8[j])*LINV;
            term += kf*qf;
        }
        float y = term - comp;
        float tt = s + y;
        comp = (tt - s) - y;
        s = tt;
    }
    for (int o=32;o>0;o>>=1) s += __shfl_down(s, o, 64);
    __shared__ float red[4];
    if ((threadIdx.x & 63)==0) red[threadIdx.x>>6] = s;
    __syncthreads();
    if (threadIdx.x==0)
        scores4[(size_t)(b*TOPC + c)*4 + chunk] = red[0]+red[1]+red[2]+red[3];
}

// ---------------- final top-6 + softmax from exact scores (wave-parallel) ----------------
__global__ __launch_bounds__(64) void finalize_k(const int* __restrict__ cand,
                                                 const float* __restrict__ scores4,
                                                 int* __restrict__ delays,
                                                 float* __restrict__ wts){
    int b = blockIdx.x;
    int lane = threadIdx.x;
    float v = -1e30f;
    int idx = 1<<30;
    if (lane < TOPC){
        size_t s4 = (size_t)(b*TOPC + lane)*4;
        v = (scores4[s4] + scores4[s4+1] + scores4[s4+2] + scores4[s4+3]) * (1.f/256.f);
        idx = cand[b*TOPC + lane];
    }
    float topv[TOPK]; int topi[TOPK];
    #pragma unroll
    for (int k=0;k<TOPK;k++){
        float bv = v; int bi = idx;
        #pragma unroll
        for (int o=8;o>0;o>>=1){
            float ov = __shfl_xor(bv, o, 16);
            int   oi = __shfl_xor(bi, o, 16);
            if (ov > bv || (ov == bv && oi < bi)){ bv = ov; bi = oi; }
        }
        topv[k]=bv; topi[k]=bi;
        if (idx == bi) v = -1e30f;
    }
    if (lane==0){
        float mx = topv[0];
        float e[TOPK], se=0.f;
        #pragma unroll
        for (int k=0;k<TOPK;k++){ e[k]=expf(topv[k]-mx); se+=e[k]; }
        #pragma unroll
        for (int k=0;k<TOPK;k++){
            wts[b*TOPK+k] = e[k]/se;
            delays[b*TOPK+k] = topi[k];
        }
    }
}

// ---------------- attention gather: v f32 -> a split pair ----------------
__global__ __launch_bounds__(256) void attn_gather4(const float4* __restrict__ v,
                                                    const int* __restrict__ delays,
                                                    const float* __restrict__ wts,
                                                    ushort* __restrict__ ah,
                                                    ushort* __restrict__ al){
    int gid = blockIdx.x*256 + threadIdx.x;
    int d4 = gid & 63;
    int bl = gid >> 6;
    int b = bl >> 10, l = bl & (LL-1);
    const int* dl = delays + b*TOPK;
    const float* w = wts + b*TOPK;
    float ax=0.f, ay=0.f, az=0.f, aw=0.f;
    #pragma unroll
    for (int kk=0;kk<TOPK;kk++){
        int ls = (l + dl[kk]) & (LL-1);
        float4 t = v[(size_t)((b<<10)+ls)*64 + d4];
        float wk = w[kk];
        ax += wk*t.x; ay += wk*t.y; az += wk*t.z; aw += wk*t.w;
    }
    storep4(ah, al, gid, make_float4(ax, ay, az, aw));
}

// ---------------- decomp: (pair + f32) - movmean5 -> pair ----------------
__global__ __launch_bounds__(256) void add_decomp_pf_p(const ushort* __restrict__ xah,
                                                       const ushort* __restrict__ xal,
                                                       const float4* __restrict__ xb,
                                                       ushort* __restrict__ oh,
                                                       ushort* __restrict__ ol){
    int d4 = threadIdx.x & 63;
    int rg = threadIdx.x >> 6;
    int b = blockIdx.x;
    int l0 = blockIdx.y*128 + rg*32;
    float4 win[5];
    #pragma unroll
    for (int i=0;i<4;i++){
        int g = l0 - 2 + i;
        g = g < 0 ? 0 : g;
        size_t idx = (size_t)((b<<10) + g)*64 + d4;
        float4 A = loadp4(xah, xal, idx), Bv = xb[idx];
        win[i] = make_float4(A.x+Bv.x, A.y+Bv.y, A.z+Bv.z, A.w+Bv.w);
    }
    for (int i=0;i<32;i++){
        int g = l0 + 2 + i;
        g = g > LL-1 ? LL-1 : g;
        size_t idx = (size_t)((b<<10) + g)*64 + d4;
        float4 A = loadp4(xah, xal, idx), Bv = xb[idx];
        win[4] = make_float4(A.x+Bv.x, A.y+Bv.y, A.z+Bv.z, A.w+Bv.w);
        float4 o;
        o.x = win[2].x - (win[0].x+win[1].x+win[2].x+win[3].x+win[4].x)*0.2f;
        o.y = win[2].y - (win[0].y+win[1].y+win[2].y+win[3].y+win[4].y)*0.2f;
        o.z = win[2].z - (win[0].z+win[1].z+win[2].z+win[3].z+win[4].z)*0.2f;
        o.w = win[2].w - (win[0].w+win[1].w+win[2].w+win[3].w+win[4].w)*0.2f;
        storep4(oh, ol, (size_t)((b<<10) + l0 + i)*64 + d4, o);
        win[0]=win[1]; win[1]=win[2]; win[2]=win[3]; win[3]=win[4];
    }
}

// decomp 3-input: (pair + f32 + f32) - movmean5 -> pair
__global__ __launch_bounds__(256) void add_decomp3_pff_p(const ushort* __restrict__ xah,
                                                         const ushort* __restrict__ xal,
                                                         const float4* __restrict__ xb,
                                                         const float4* __restrict__ xc,
                                                         ushort* __restrict__ oh,
                                                         ushort* __restrict__ ol){
    int d4 = threadIdx.x & 63;
    int rg = threadIdx.x >> 6;
    int b = blockIdx.x;
    int l0 = blockIdx.y*128 + rg*32;
    float4 win[5];
    #pragma unroll
    for (int i=0;i<4;i++){
        int g = l0 - 2 + i;
        g = g < 0 ? 0 : g;
        size_t idx = (size_t)((b<<10) + g)*64 + d4;
        float4 A = loadp4(xah, xal, idx), Bv = xb[idx], Cc = xc[idx];
        win[i] = make_float4(A.x+Bv.x+Cc.x, A.y+Bv.y+Cc.y, A.z+Bv.z+Cc.z, A.w+Bv.w+Cc.w);
    }
    for (int i=0;i<32;i++){
        int g = l0 + 2 + i;
        g = g > LL-1 ? LL-1 : g;
        size_t idx = (size_t)((b<<10) + g)*64 + d4;
        float4 A = loadp4(xah, xal, idx), Bv = xb[idx], Cc = xc[idx];
        win[4] = make_float4(A.x+Bv.x+Cc.x, A.y+Bv.y+Cc.y, A.z+Bv.z+Cc.z, A.w+Bv.w+Cc.w);
        float4 o;
        o.x = win[2].x - (win[0].x+win[1].x+win[2].x+win[3].x+win[4].x)*0.2f;
        o.y = win[2].y - (win[0].y+win[1].y+win[2].y+win[3].y+win[4].y)*0.2f;
        o.z = win[2].z - (win[0].z+win[1].z+win[2].z+win[3].z+win[4].z)*0.2f;
        o.w = win[2].w - (win[0].w+win[1].w+win[2].w+win[3].w+win[4].w)*0.2f;
        storep4(oh, ol, (size_t)((b<<10) + l0 + i)*64 + d4, o);
        win[0]=win[1]; win[1]=win[2]; win[2]=win[3]; win[3]=win[4];
    }
}

// ---------------- layernorm over d per (b,l), pair input ----------------
__global__ __launch_bounds__(256) void ln_kernel(const ushort* __restrict__ xh_,
                                                 const ushort* __restrict__ xl_,
                                                 const float* __restrict__ nw,
                                                 const float* __restrict__ nb,
                                                 float* __restrict__ xh){
    int bl = blockIdx.x, d = threadIdx.x;
    size_t i = (size_t)bl*DM + d;
    float val = h2f(xh_[i]) + h2f(xl_[i])*LINV;
    __shared__ float red[4];
    float v = val;
    for (int o=32;o>0;o>>=1) v += __shfl_down(v, o, 64);
    if ((d&63)==0) red[d>>6] = v;
    __syncthreads();
    float mu = (red[0]+red[1]+red[2]+red[3])*(1.f/256.f);
    __syncthreads();
    float diff = val - mu;
    v = diff*diff;
    for (int o=32;o>0;o>>=1) v += __shfl_down(v, o, 64);
    if ((d&63)==0) red[d>>6] = v;
    __syncthreads();
    float var = (red[0]+red[1]+red[2]+red[3])*(1.f/256.f);
    xh[i] = diff*rsqrtf(var+1e-5f)*nw[d] + nb[d];
}

// ---------------- column sums over l ----------------
__global__ __launch_bounds__(256) void colsum_kernel(const float* __restrict__ xh,
                                                     float* __restrict__ colsum){
    int b = blockIdx.x, chunk = blockIdx.y, d = threadIdx.x;
    float s = 0.f;
    for (int l = chunk*128; l < (chunk+1)*128; l++)
        s += xh[((size_t)b*LL + l)*DM + d];
    atomicAdd(&colsum[b*DM + d], s);
}

// ---------------- g = gelu(xh - colmean) ----------------
__global__ __launch_bounds__(256) void gelu_sub_kernel(const float* __restrict__ xh,
                                                       const float* __restrict__ colsum,
                                                       float* __restrict__ g){
    int bl = blockIdx.x, d = threadIdx.x;
    int b = bl / LL;
    float v = xh[(size_t)bl*DM + d] - colsum[b*DM + d]*(1.f/1024.f);
    g[(size_t)bl*DM + d] = gelu_f(v);
}

// ---------------- final projection ----------------
__global__ __launch_bounds__(256) void proj_kernel(const float* __restrict__ g,
                                                   const float* __restrict__ pw,
                                                   const float* __restrict__ pb,
                                                   float* __restrict__ out){
    int b = blockIdx.x, c = blockIdx.y, ch = blockIdx.z;
    int tid = threadIdx.x;
    const size_t F = (size_t)LL*DM;
    size_t base = ch*(F/16);
    float s = 0.f;
    for (size_t i = tid; i < F/16; i += 256)
        s += g[(size_t)b*F + base + i] * pw[(size_t)c*F + base + i];
    for (int o=32;o>0;o>>=1) s += __shfl_down(s, o, 64);
    __shared__ float red[4];
    if ((tid&63)==0) red[tid>>6] = s;
    __syncthreads();
    if (tid==0){
        float tot = red[0]+red[1]+red[2]+red[3];
        if (ch==0) tot += pb[c];
        atomicAdd(&out[b*3 + c], tot);
    }
}

extern "C" void kernel_launch(void* const* d_in, const int* in_sizes, int n_in,
                              void* d_out, int out_size, void* d_ws, size_t ws_size,
                              hipStream_t stream) {
    const float* x_enc   = (const float*)d_in[0];
    const float* token_w = (const float*)d_in[1];
    const float* qw = (const float*)d_in[2];
    const float* qb = (const float*)d_in[3];
    const float* kw = (const float*)d_in[4];
    const float* kb = (const float*)d_in[5];
    const float* vw = (const float*)d_in[6];
    const float* vb = (const float*)d_in[7];
    const float* ow = (const float*)d_in[8];
    const float* ob = (const float*)d_in[9];
    const float* c1w = (const float*)d_in[10];
    const float* c2w = (const float*)d_in[11];
    const float* norm_w = (const float*)d_in[12];
    const float* norm_b = (const float*)d_in[13];
    const float* proj_w = (const float*)d_in[14];
    const float* proj_b = (const float*)d_in[15];
    float* outp = (float*)d_out;

    const size_t NTOK = (size_t)BB*LL*DM;        // 8388608
    float* ws = (float*)d_ws;
    float* buf0 = ws;            // x pair / y pair
    float* buf1 = ws + NTOK;     // q pair / a pair / x1 pair / ln-out f32
    float* buf2 = ws + 2*NTOK;   // k pair / o f32 / y2 f32 / gelu f32
    ushort* wu = (ushort*)(ws + 3*NTOK);
    const size_t WSM = (size_t)NLAYERS*DM*DM;    // 196608
    const size_t WSF = (size_t)NLAYERS*DFF*DM;   // 786432
    // qkv combined: [3][768][256] pairs
    ushort* qkvwh = wu;              ushort* qkvwl = qkvwh + 3*WSM;
    ushort* owh  = qkvwl + 3*WSM;    ushort* owl  = owh + WSM;
    ushort* c1wh = owl + WSM;        ushort* c1wl = c1wh + WSF;
    ushort* c2wh = c1wl + WSF;       ushort* c2wl = c2wh + WSF;
    // total ushorts: 8*WSM + 4*WSF = 4718592 -> 2359296 floats (unchanged)
    float* after_w = ws + 3*NTOK + 2359296;
    float* qkvbias = after_w;                       // 3*768
    float* colsum = qkvbias + (size_t)NLAYERS*768;  // 8192
    int*   delays = (int*)(colsum + BB*DM);         // 192
    float* wts    = (float*)(delays + BB*TOPK);     // 192
    int*   cand   = (int*)(wts + BB*TOPK);          // 512
    float* scores4 = (float*)(cand + BB*TOPC);      // 2048
    float* twT    = scores4 + BB*TOPC*4;            // 16128
    float* scr    = twT + 63*256;                   // 524288
    float* buf3   = scr + 524288;                   // v f32 / FFN2 partial f32

    const size_t needed_floats = 3*NTOK + 2359296 + (size_t)NLAYERS*768 + (size_t)BB*DM
                               + (size_t)BB*TOPK*2 + (size_t)BB*TOPC
                               + (size_t)BB*TOPC*4 + 63*256 + 524288 + NTOK;
    const bool zs = (ws_size >= needed_floats*sizeof(float));

    hipMemsetAsync(d_out, 0, 96*sizeof(float), stream);

    {
        int n1 = NLAYERS*DM*DM;
        int n2 = NLAYERS*DFF*DM;
        // qkv combined weights: layer stride 768*256=196608; q@0, k@65536, v@131072
        split_w_strided<<<(n1+255)/256, 256, 0, stream>>>(qw, qkvwh, qkvwl, n1, 65536, 196608, 0);
        split_w_strided<<<(n1+255)/256, 256, 0, stream>>>(kw, qkvwh, qkvwl, n1, 65536, 196608, 65536);
        split_w_strided<<<(n1+255)/256, 256, 0, stream>>>(vw, qkvwh, qkvwl, n1, 65536, 196608, 131072);
        cat_bias3_k<<<(NLAYERS*768+255)/256, 256, 0, stream>>>(qb, kb, vb, qkvbias, NLAYERS*768);
        split_w_k<<<(n1+255)/256, 256, 0, stream>>>(ow, owh, owl, n1);
        split_w_k<<<(n2+255)/256, 256, 0, stream>>>(c1w, c1wh, c1wl, n2);
        split_w_k<<<(n2+255)/256, 256, 0, stream>>>(c2w, c2wh, c2wl, n2);
        transpose_tw<<<(256*63+255)/256, 256, 0, stream>>>(token_w, twT);
    }

    // x pair in buf0
    ushort* xh_p = (ushort*)buf0;  ushort* xl_p = xh_p + NTOK;
    token_embed_k<<<dim3(BB, LL/32), 256, 0, stream>>>(x_enc, twT, xh_p, xl_p);

    const int M = BB*LL;  // 32768
    const int FFNC = 8192;

    for (int l=0; l<NLAYERS; l++){
        ushort* qkvwh_l = qkvwh + (size_t)l*768*DM; ushort* qkvwl_l = qkvwl + (size_t)l*768*DM;
        ushort* owh_l = owh + (size_t)l*DM*DM;      ushort* owl_l = owl + (size_t)l*DM*DM;
        ushort* c1wh_l = c1wh + (size_t)l*DFF*DM;   ushort* c1wl_l = c1wl + (size_t)l*DFF*DM;
        ushort* c2wh_l = c2wh + (size_t)l*DM*DFF;   ushort* c2wl_l = c2wl + (size_t)l*DM*DFF;
        const float* qkvb_l = qkvbias + (size_t)l*768;
        const float* ob_l = ob + (size_t)l*DM;

        // fused q+k+v -> buf1 pair (q), buf2 pair (k), buf3 f32 (v)
        ushort* qh_p = (ushort*)buf1;  ushort* ql_p = qh_p + NTOK;
        ushort* kh_p = (ushort*)buf2;  ushort* kl_p = kh_p + NTOK;
        gemm_mfma_split<true,false,4,false><<<(M/128)*(768/64), 256, 0, stream>>>(
            xh_p, xl_p, qkvwh_l, qkvwl_l, qkvb_l, qh_p, ql_p, kh_p, kl_p, buf3, M, 768, DM);

        // approx corr -> fused reduce+candidates -> exact rescore -> top-6
        corr_mfma<<<2048, 256, 0, stream>>>(qh_p, kh_p, scr);
        corr_sel<<<BB, 256, 0, stream>>>(scr, cand);
        rescore_k<<<dim3(BB*TOPC, 4), 256, 0, stream>>>(qh_p, ql_p, kh_p, kl_p, cand, scores4);
        finalize_k<<<BB, 64, 0, stream>>>(cand, scores4, delays, wts);

        // a pair -> buf1 (q dead), o f32 -> buf2 (k dead)
        ushort* ah_p = (ushort*)buf1;  ushort* al_p = ah_p + NTOK;
        attn_gather4<<<(BB*LL*64)/256, 256, 0, stream>>>(
            (const float4*)buf3, delays, wts, ah_p, al_p);
        gemm_mfma_split<true,false,0,false><<<(M/128)*(DM/64), 256, 0, stream>>>(
            ah_p, al_p, owh_l, owl_l, ob_l, buf2, nullptr, nullptr, nullptr, nullptr, M, DM, DM);

        // x1 pair = (x + o) - movmean -> buf1 (a dead)
        ushort* x1h_p = (ushort*)buf1;  ushort* x1l_p = x1h_p + NTOK;
        add_decomp_pf_p<<<dim3(BB, LL/128), 256, 0, stream>>>(
            xh_p, xl_p, (const float4*)buf2, x1h_p, x1l_p);

        // FFN chunked: y pair in buf0 (x dead); y2 f32 -> buf2 (+ buf3 partial when zs)
        ushort* yh_p = (ushort*)buf0;
        ushort* yl_p = yh_p + (size_t)FFNC*DFF;
        for (int c0 = 0; c0 < M; c0 += FFNC){
            gemm_mfma_split<false,true,2,false><<<(FFNC/128)*(DFF/64), 256, 0, stream>>>(
                x1h_p + (size_t)c0*DM, x1l_p + (size_t)c0*DM, c1wh_l, c1wl_l, nullptr,
                yh_p, yl_p, nullptr, nullptr, nullptr, FFNC, DFF, DM);
            if (zs){
                gemm_mfma_split<false,false,0,true><<<dim3((FFNC/128)*(DM/64), 2), 256, 0, stream>>>(
                    yh_p, yl_p, c2wh_l, c2wl_l, nullptr,
                    buf2 + (size_t)c0*DM, buf3 + (size_t)c0*DM, nullptr, nullptr, nullptr, FFNC, DM, DFF);
            } else {
                gemm_mfma_split<false,false,0,false><<<(FFNC/128)*(DM/64), 256, 0, stream>>>(
                    yh_p, yl_p, c2wh_l, c2wl_l, nullptr,
                    buf2 + (size_t)c0*DM, nullptr, nullptr, nullptr, nullptr, FFNC, DM, DFF);
            }
        }

        // x pair = (x1 + y2 [+partial]) - movmean -> buf0 (y dead)
        if (zs)
            add_decomp3_pff_p<<<dim3(BB, LL/128), 256, 0, stream>>>(
                x1h_p, x1l_p, (const float4*)buf2, (const float4*)buf3, xh_p, xl_p);
        else
            add_decomp_pf_p<<<dim3(BB, LL/128), 256, 0, stream>>>(
                x1h_p, x1l_p, (const float4*)buf2, xh_p, xl_p);
    }

    // final layernorm (pair in) -> buf1 f32
    ln_kernel<<<BB*LL, 256, 0, stream>>>(xh_p, xl_p, norm_w, norm_b, buf1);
    hipMemsetAsync(colsum, 0, (size_t)BB*DM*sizeof(float), stream);
    colsum_kernel<<<dim3(BB, 8), 256, 0, stream>>>(buf1, colsum);
    gelu_sub_kernel<<<BB*LL, 256, 0, stream>>>(buf1, colsum, buf2);
    proj_kernel<<<dim3(BB, 3, 16), 256, 0, stream>>>(buf2, proj_w, proj_b, outp);
}

// Round 18
// 1782.232 us; speedup vs baseline: 1.0332x; 1.0305x over previous
//
#include <hip/hip_runtime.h>
#include <hip/hip_bf16.h>
#include <math.h>

// Problem constants
#define BB 32
#define LL 1024
#define C_IN 21
#define DM 256
#define DFF 1024
#define NLAYERS 3
#define TOPK 6
#define TOPC 16
#define LSCALE 4096.0f
#define LINV (1.0f/4096.0f)

typedef __attribute__((ext_vector_type(8))) short short8v;
typedef __attribute__((ext_vector_type(8))) _Float16 half8;
typedef __attribute__((ext_vector_type(4))) float f32x4;

__device__ __forceinline__ float gelu_f(float v){
    return 0.5f * v * (1.0f + erff(v * 0.7071067811865476f));
}
__device__ __forceinline__ ushort f2h_bits(float f){
    _Float16 h = (_Float16)f;
    return __builtin_bit_cast(ushort, h);
}
__device__ __forceinline__ float h2f(ushort u){
    return (float)__builtin_bit_cast(_Float16, u);
}
// direct global->LDS 16B copy (wave-uniform LDS base + lane*16)
__device__ __forceinline__ void lds16(const ushort* g, ushort* l){
    __builtin_amdgcn_global_load_lds(
        (const __attribute__((address_space(1))) void*)g,
        (__attribute__((address_space(3))) void*)l, 16, 0, 0);
}
// split-pair helpers (4 elements)
__device__ __forceinline__ float4 loadp4(const ushort* __restrict__ h, const ushort* __restrict__ l, size_t i4){
    ushort4 hv = *reinterpret_cast<const ushort4*>(h + 4*i4);
    ushort4 lv = *reinterpret_cast<const ushort4*>(l + 4*i4);
    return make_float4(h2f(hv.x)+h2f(lv.x)*LINV, h2f(hv.y)+h2f(lv.y)*LINV,
                       h2f(hv.z)+h2f(lv.z)*LINV, h2f(hv.w)+h2f(lv.w)*LINV);
}
__device__ __forceinline__ void storep4(ushort* __restrict__ h, ushort* __restrict__ l, size_t i4, float4 v){
    ushort4 hv, lv;
    _Float16 a;
    a=(_Float16)v.x; hv.x=__builtin_bit_cast(ushort,a); lv.x=f2h_bits((v.x-(float)a)*LSCALE);
    a=(_Float16)v.y; hv.y=__builtin_bit_cast(ushort,a); lv.y=f2h_bits((v.y-(float)a)*LSCALE);
    a=(_Float16)v.z; hv.z=__builtin_bit_cast(ushort,a); lv.z=f2h_bits((v.z-(float)a)*LSCALE);
    a=(_Float16)v.w; hv.w=__builtin_bit_cast(ushort,a); lv.w=f2h_bits((v.w-(float)a)*LSCALE);
    *reinterpret_cast<ushort4*>(h + 4*i4) = hv;
    *reinterpret_cast<ushort4*>(l + 4*i4) = lv;
}

// ---------------- weight conversion: f16 hi + 4096*lo ----------------
__global__ __launch_bounds__(256) void split_w_k(const float* __restrict__ src,
                                                 ushort* __restrict__ h, ushort* __restrict__ l, int n){
    int i = blockIdx.x*256 + threadIdx.x;
    if (i < n){
        float f = src[i];
        _Float16 hh = (_Float16)f;
        h[i] = __builtin_bit_cast(ushort, hh);
        l[i] = f2h_bits((f - (float)hh) * LSCALE);
    }
}
__global__ __launch_bounds__(256) void split_w_strided(const float* __restrict__ src,
                                                       ushort* __restrict__ h, ushort* __restrict__ l,
                                                       int n, int src_ls, int dst_ls, int dst_off){
    int i = blockIdx.x*256 + threadIdx.x;
    if (i < n){
        int layer = i / src_ls, r = i % src_ls;
        float f = src[i];
        _Float16 hh = (_Float16)f;
        size_t d = (size_t)layer*dst_ls + dst_off + r;
        h[d] = __builtin_bit_cast(ushort, hh);
        l[d] = f2h_bits((f - (float)hh) * LSCALE);
    }
}
__global__ __launch_bounds__(256) void cat_bias3_k(const float* __restrict__ b1,
                                                   const float* __restrict__ b2,
                                                   const float* __restrict__ b3,
                                                   float* __restrict__ out, int n){ // n = 3*768
    int i = blockIdx.x*256 + threadIdx.x;
    if (i < n){
        int layer = i / 768, c = i % 768;
        out[i] = (c < 256) ? b1[layer*256 + c]
               : (c < 512) ? b2[layer*256 + c - 256]
                           : b3[layer*256 + c - 512];
    }
}
// transpose token weight [256][63] -> [63][256]
__global__ __launch_bounds__(256) void transpose_tw(const float* __restrict__ src,
                                                    float* __restrict__ dst){
    int i = blockIdx.x*256 + threadIdx.x;
    if (i < 256*63){
        int d = i / 63, k = i % 63;
        dst[k*256 + d] = src[i];
    }
}

// ---------------- token embedding: circular conv1d k=3, split-pair output ----------------
__global__ __launch_bounds__(256) void token_embed_k(const float* __restrict__ x,
                                                     const float* __restrict__ wT,
                                                     ushort* __restrict__ oh,
                                                     ushort* __restrict__ ol){
    int b = blockIdx.x, l0 = blockIdx.y*32;
    int d = threadIdx.x;
    __shared__ float xs[34][C_IN];
    for (int i = threadIdx.x; i < 34*C_IN; i += 256){
        int r = i / C_IN, c = i % C_IN;
        int g = (l0 - 1 + r + LL) & (LL-1);
        xs[r][c] = x[(size_t)b*LL*C_IN + (size_t)g*C_IN + c];
    }
    float w[63];
    #pragma unroll
    for (int k=0;k<63;k++) w[k] = wT[k*256 + d];
    __syncthreads();
    for (int i=0;i<32;i++){
        float acc = 0.f;
        #pragma unroll
        for (int c=0;c<C_IN;c++){
            acc += xs[i][c]   * w[c*3+0];
            acc += xs[i+1][c] * w[c*3+1];
            acc += xs[i+2][c] * w[c*3+2];
        }
        size_t idx = ((size_t)b*LL + l0+i)*DM + d;
        _Float16 hh = (_Float16)acc;
        oh[idx] = __builtin_bit_cast(ushort, hh);
        ol[idx] = f2h_bits((acc - (float)hh) * LSCALE);
    }
}

// =================== split-f16 MFMA GEMM, 128x64, double-buffered global_load_lds (2-phase) ===================
// OMODE: 0 = f32 out (Cv), 2 = split pair out (Cv,C2v),
//        4 = fused qkv: col<256 -> q pair (Cv,C2v), col<512 -> k pair (C3v,C4v), else v f32 (C5v)
template<bool BIAS, bool GELU, int OMODE, bool ZSPLIT>
__global__ __launch_bounds__(256) void gemm_mfma_split(const ushort* __restrict__ Ah_g,
                                                       const ushort* __restrict__ Al_g,
                                                       const ushort* __restrict__ Wh,
                                                       const ushort* __restrict__ Wl,
                                                       const float* __restrict__ bias,
                                                       void* __restrict__ Cv,
                                                       void* __restrict__ C2v,
                                                       void* __restrict__ C3v,
                                                       void* __restrict__ C4v,
                                                       void* __restrict__ C5v,
                                                       int M, int N, int K){
    __shared__ __align__(16) ushort Ah_s[2][128*32];
    __shared__ __align__(16) ushort Al_s[2][128*32];
    __shared__ __align__(16) ushort Wh_s[2][64*32];
    __shared__ __align__(16) ushort Wl_s[2][64*32];

    const int tid = threadIdx.x;
    const int MB = M >> 7;
    const int bx = blockIdx.x % MB, by = blockIdx.x / MB;
    const int bm = bx << 7, bn = by << 6;

    const int lane = tid & 63;
    const int wid  = tid >> 6;
    const int wm = wid >> 1, wn = wid & 1;
    const int lr = lane & 15, lg = lane >> 4;

    int aoff[4], boff[2];
    #pragma unroll
    for (int f=0; f<4; f++){
        int ar = wm*64 + f*16 + lr;
        aoff[f] = ar*32 + (lg ^ ((ar>>1)&3))*8;
    }
    #pragma unroll
    for (int g=0; g<2; g++){
        int br = wn*32 + g*16 + lr;
        boff[g] = br*32 + (lg ^ ((br>>1)&3))*8;
    }

    f32x4 acc[4][2], accX[4][2];
    #pragma unroll
    for (int i=0;i<4;i++)
        #pragma unroll
        for (int j=0;j<2;j++){
            acc[i][j]  = (f32x4){0.f,0.f,0.f,0.f};
            accX[i][j] = (f32x4){0.f,0.f,0.f,0.f};
        }

    const int kbeg = ZSPLIT ? (int)blockIdx.y * (K>>1) : 0;
    const int kend = ZSPLIT ? kbeg + (K>>1) : K;
    const int wbase = (tid & 192);   // wave-uniform

    auto stage = [&](int bufi, int k0){
        #pragma unroll
        for (int i=0;i<2;i++){
            int c = i*256 + tid;
            int row = c >> 2, ko = c & 3;
            int sw = ko ^ ((row>>1)&3);
            size_t src = (size_t)(bm+row)*K + k0 + sw*8;
            int ldso = (i*256 + wbase)*8;
            lds16(Ah_g + src, &Ah_s[bufi][ldso]);
            lds16(Al_g + src, &Al_s[bufi][ldso]);
        }
        {
            int row = tid >> 2, ko = tid & 3;
            int sw = ko ^ ((row>>1)&3);
            size_t src = (size_t)(bn+row)*K + k0 + sw*8;
            lds16(Wh + src, &Wh_s[bufi][wbase*8]);
            lds16(Wl + src, &Wl_s[bufi][wbase*8]);
        }
    };

    stage(0, kbeg);
    __syncthreads();

    int cur = 0;
    for (int k0=kbeg; k0<kend; k0+=32){
        if (k0 + 32 < kend) stage(cur^1, k0+32);   // prefetch next tile (in flight during MFMA)

        short8v af[4], al[4], bf_[2], bl[2];
        #pragma unroll
        for (int f=0; f<4; f++){
            af[f] = *reinterpret_cast<short8v*>(&Ah_s[cur][aoff[f]]);
            al[f] = *reinterpret_cast<short8v*>(&Al_s[cur][aoff[f]]);
        }
        #pragma unroll
        for (int g=0; g<2; g++){
            bf_[g] = *reinterpret_cast<short8v*>(&Wh_s[cur][boff[g]]);
            bl[g]  = *reinterpret_cast<short8v*>(&Wl_s[cur][boff[g]]);
        }
        #pragma unroll
        for (int i=0;i<4;i++){
            #pragma unroll
            for (int j=0;j<2;j++){
                acc[i][j] = __builtin_amdgcn_mfma_f32_16x16x32_f16(
                    __builtin_bit_cast(half8, af[i]), __builtin_bit_cast(half8, bf_[j]), acc[i][j], 0,0,0);
                accX[i][j] = __builtin_amdgcn_mfma_f32_16x16x32_f16(
                    __builtin_bit_cast(half8, af[i]), __builtin_bit_cast(half8, bl[j]), accX[i][j], 0,0,0);
                accX[i][j] = __builtin_amdgcn_mfma_f32_16x16x32_f16(
                    __builtin_bit_cast(half8, al[i]), __builtin_bit_cast(half8, bf_[j]), accX[i][j], 0,0,0);
            }
        }
        __syncthreads();   // drains prefetch (vmcnt) + protects buf reuse
        cur ^= 1;
    }

    // ---- epilogue ----
    float* Cout0 = (float*)((ZSPLIT && blockIdx.y) ? C2v : Cv);
    const int crow0 = bm + wm*64, ccol0 = bn + wn*32;
    #pragma unroll
    for (int i=0;i<4;i++){
        #pragma unroll
        for (int j=0;j<2;j++){
            int row0 = crow0 + i*16 + lg*4;
            int col  = ccol0 + j*16 + lr;
            float bv = (BIAS && (!ZSPLIT || blockIdx.y==0)) ? bias[col] : 0.f;
            #pragma unroll
            for (int r=0;r<4;r++){
                float v = acc[i][j][r] + accX[i][j][r]*LINV + bv;
                if (GELU) v = gelu_f(v);
                if (OMODE == 0){
                    Cout0[(size_t)(row0+r)*N + col] = v;
                } else if (OMODE == 2){
                    size_t idx = (size_t)(row0+r)*N + col;
                    _Float16 hh = (_Float16)v;
                    ((ushort*)Cv)[idx]  = __builtin_bit_cast(ushort, hh);
                    ((ushort*)C2v)[idx] = f2h_bits((v - (float)hh) * LSCALE);
                } else { // OMODE 4: fused qkv, out stride 256
                    if (col < 512){
                        _Float16 hh = (_Float16)v;
                        ushort hb = __builtin_bit_cast(ushort, hh);
                        ushort lb = f2h_bits((v - (float)hh) * LSCALE);
                        if (col < 256){
                            size_t idx = (size_t)(row0+r)*256 + col;
                            ((ushort*)Cv)[idx]  = hb;
                            ((ushort*)C2v)[idx] = lb;
                        } else {
                            size_t idx = (size_t)(row0+r)*256 + (col-256);
                            ((ushort*)C3v)[idx] = hb;
                            ((ushort*)C4v)[idx] = lb;
                        }
                    } else {
                        ((float*)C5v)[(size_t)(row0+r)*256 + (col-512)] = v;
                    }
                }
            }
        }
    }
}

// =================== corr (APPROX, hi-plane): 128x128 Gram tile, double-buffered staging ===================
__global__ __launch_bounds__(256) void corr_mfma(const ushort* __restrict__ qh,
                                                 const ushort* __restrict__ kh,
                                                 float* __restrict__ scr){
    __shared__ __align__(16) ushort Qh_s[2][128*32];
    __shared__ __align__(16) ushort Kh_s[2][128*32];
    __shared__ float bins[255];

    const int tid = threadIdx.x;
    int flat = blockIdx.x;
    flat = (flat & 7) * 256 + (flat >> 3);   // XCD-aware swizzle
    const int bxt = flat & 7;
    const int byt = (flat >> 3) & 7;
    const int b   = flat >> 6;
    const int bi = bxt * 128, bj = byt * 128;

    for (int i=tid; i<255; i+=256) bins[i] = 0.f;

    const int lane = tid & 63;
    const int wid  = tid >> 6;
    const int wm = wid >> 1, wn = wid & 1;
    const int lr = lane & 15, lg = lane >> 4;

    int aoff[4], boff[4];
    #pragma unroll
    for (int f=0; f<4; f++){
        int ar = wm*64 + f*16 + lr;
        aoff[f] = ar*32 + (lg ^ ((ar>>1)&3))*8;
        int br = wn*64 + f*16 + lr;
        boff[f] = br*32 + (lg ^ ((br>>1)&3))*8;
    }

    f32x4 acc[4][4];
    #pragma unroll
    for (int i=0;i<4;i++)
        #pragma unroll
        for (int j=0;j<4;j++)
            acc[i][j] = (f32x4){0.f,0.f,0.f,0.f};

    const size_t qbase = (size_t)b*LL*DM;
    const int wbase = (tid & 192);

    auto stage = [&](int bufi, int k0){
        #pragma unroll
        for (int i=0;i<2;i++){
            int c = i*256 + tid;
            int row = c >> 2, ko = c & 3;
            int sw = ko ^ ((row>>1)&3);
            size_t qsrc = qbase + (size_t)(bi+row)*DM + k0 + sw*8;
            size_t ksrc = qbase + (size_t)(bj+row)*DM + k0 + sw*8;
            int ldso = (i*256 + wbase)*8;
            lds16(qh + qsrc, &Qh_s[bufi][ldso]);
            lds16(kh + ksrc, &Kh_s[bufi][ldso]);
        }
    };

    stage(0, 0);
    __syncthreads();

    int cur = 0;
    for (int k0=0; k0<DM; k0+=32){
        if (k0 + 32 < DM) stage(cur^1, k0+32);

        short8v ah[4], bh4[4];
        #pragma unroll
        for (int f=0; f<4; f++){
            ah[f]  = *reinterpret_cast<short8v*>(&Qh_s[cur][aoff[f]]);
            bh4[f] = *reinterpret_cast<short8v*>(&Kh_s[cur][boff[f]]);
        }
        #pragma unroll
        for (int i=0;i<4;i++)
            #pragma unroll
            for (int j=0;j<4;j++)
                acc[i][j] = __builtin_amdgcn_mfma_f32_16x16x32_f16(
                    __builtin_bit_cast(half8, ah[i]), __builtin_bit_cast(half8, bh4[j]), acc[i][j], 0,0,0);
        __syncthreads();
        cur ^= 1;
    }

    float pre[7][4];
    #pragma unroll
    for (int d=0; d<7; d++)
        #pragma unroll
        for (int r=0;r<4;r++) pre[d][r]=0.f;
    #pragma unroll
    for (int i=0;i<4;i++)
        #pragma unroll
        for (int j=0;j<4;j++)
            #pragma unroll
            for (int r=0;r<4;r++)
                pre[i-j+3][r] += acc[i][j][r];
    const int bbase = wm*64 - wn*64 + lg*4 - lr + 127;
    #pragma unroll
    for (int d=0; d<7; d++)
        #pragma unroll
        for (int r=0;r<4;r++)
            atomicAdd(&bins[bbase + 16*(d-3) + r], pre[d][r]);
    __syncthreads();
    float* slot = scr + ((size_t)(b*64 + byt*8 + bxt) << 8);
    for (int i=tid; i<255; i+=256) slot[i] = bins[i];
}

// ---------------- fused: deterministic tile-bin reduce + top-16 candidates ----------------
__global__ __launch_bounds__(256) void corr_sel(const float* __restrict__ scr,
                                                int* __restrict__ cand){
    int b = blockIdx.x, tid = threadIdx.x;
    __shared__ float sv[LL];
    __shared__ float rv[256];
    __shared__ int ri[256];
    const float* base = scr + ((size_t)b << 14);
    for (int t = tid; t < LL; t += 256){
        float s = 0.f;
        #pragma unroll
        for (int byt=0; byt<8; byt++){
            #pragma unroll
            for (int bxt=0; bxt<8; bxt++){
                int i = (t - 128*(bxt - byt) + 127) & (LL-1);
                if (i < 255) s += base[((byt*8 + bxt) << 8) + i];
            }
        }
        sv[t] = s * (1.f/256.f);
    }
    __syncthreads();
    for (int it=0; it<TOPC; it++){
        float best = -1e30f; int bi = LL;
        for (int i=tid;i<LL;i+=256){
            float v = sv[i];
            if (v > best || (v == best && i < bi)){ best = v; bi = i; }
        }
        rv[tid]=best; ri[tid]=bi;
        __syncthreads();
        for (int s=128;s>0;s>>=1){
            if (tid < s){
                if (rv[tid+s] > rv[tid] || (rv[tid+s]==rv[tid] && ri[tid+s]<ri[tid])){
                    rv[tid]=rv[tid+s]; ri[tid]=ri[tid+s];
                }
            }
            __syncthreads();
        }
        if (tid==0){ cand[b*TOPC+it]=ri[0]; sv[ri[0]] = -1e30f; }
        __syncthreads();
    }
}

// ---------------- exact rescore of candidates: f32 reconstruct + Kahan, 4-way M-split ----------------
__global__ __launch_bounds__(256) void rescore_k(const ushort* __restrict__ qh,
                                                 const ushort* __restrict__ ql,
                                                 const ushort* __restrict__ kh,
                                                 const ushort* __restrict__ kl,
                                                 const int* __restrict__ cand,
                                                 float* __restrict__ scores4){
    int i = blockIdx.x;
    int b = (i & 7) | (((i >> 3) & 3) << 3);
    int c = i >> 5;
    int chunk = blockIdx.y;
    int t = cand[b*TOPC + c];
    const size_t base = (size_t)b << 18;
    const int off = t << 8;
    const int mbeg = chunk << 16;
    const int mend = mbeg + (1<<16);
    float s = 0.f, comp = 0.f;
    for (int m = mbeg + threadIdx.x*8; m < mend; m += 256*8){
        int mq = (m + off) & ((1<<18)-1);
        short8v kh8 = *reinterpret_cast<const short8v*>(kh + base + m);
        short8v kl8 = *reinterpret_cast<const short8v*>(kl + base + m);
        short8v qh8 = *reinterpret_cast<const short8v*>(qh + base + mq);
        short8v ql8 = *reinterpret_cast<const short8v*>(ql + base + mq);
        float term = 0.f;
        #pragma unroll
        for (int j=0;j<8;j++){
            float kf = h2f((ushort)kh8[j]) + h2f((ushort)kl8[j])*LINV;
            float qf = h2f((ushort)qh8[j]) + h2f((ushort)ql8[j])*LINV;
            term += kf*qf;
        }
        float y = term - comp;
        float tt = s + y;
        comp = (tt - s) - y;
        s = tt;
    }
    for (int o=32;o>0;o>>=1) s += __shfl_down(s, o, 64);
    __shared__ float red[4];
    if ((threadIdx.x & 63)==0) red[threadIdx.x>>6] = s;
    __syncthreads();
    if (threadIdx.x==0)
        scores4[(size_t)(b*TOPC + c)*4 + chunk] = red[0]+red[1]+red[2]+red[3];
}

// ---------------- final top-6 + softmax from exact scores (wave-parallel) ----------------
__global__ __launch_bounds__(64) void finalize_k(const int* __restrict__ cand,
                                                 const float* __restrict__ scores4,
                                                 int* __restrict__ delays,
                                                 float* __restrict__ wts){
    int b = blockIdx.x;
    int lane = threadIdx.x;
    float v = -1e30f;
    int idx = 1<<30;
    if (lane < TOPC){
        size_t s4 = (size_t)(b*TOPC + lane)*4;
        v = (scores4[s4] + scores4[s4+1] + scores4[s4+2] + scores4[s4+3]) * (1.f/256.f);
        idx = cand[b*TOPC + lane];
    }
    float topv[TOPK]; int topi[TOPK];
    #pragma unroll
    for (int k=0;k<TOPK;k++){
        float bv = v; int bi = idx;
        #pragma unroll
        for (int o=8;o>0;o>>=1){
            float ov = __shfl_xor(bv, o, 16);
            int   oi = __shfl_xor(bi, o, 16);
            if (ov > bv || (ov == bv && oi < bi)){ bv = ov; bi = oi; }
        }
        topv[k]=bv; topi[k]=bi;
        if (idx == bi) v = -1e30f;
    }
    if (lane==0){
        float mx = topv[0];
        float e[TOPK], se=0.f;
        #pragma unroll
        for (int k=0;k<TOPK;k++){ e[k]=expf(topv[k]-mx); se+=e[k]; }
        #pragma unroll
        for (int k=0;k<TOPK;k++){
            wts[b*TOPK+k] = e[k]/se;
            delays[b*TOPK+k] = topi[k];
        }
    }
}

// ---------------- attention gather: v f32 -> a split pair ----------------
__global__ __launch_bounds__(256) void attn_gather4(const float4* __restrict__ v,
                                                    const int* __restrict__ delays,
                                                    const float* __restrict__ wts,
                                                    ushort* __restrict__ ah,
                                                    ushort* __restrict__ al){
    int gid = blockIdx.x*256 + threadIdx.x;
    int d4 = gid & 63;
    int bl = gid >> 6;
    int b = bl >> 10, l = bl & (LL-1);
    const int* dl = delays + b*TOPK;
    const float* w = wts + b*TOPK;
    float ax=0.f, ay=0.f, az=0.f, aw=0.f;
    #pragma unroll
    for (int kk=0;kk<TOPK;kk++){
        int ls = (l + dl[kk]) & (LL-1);
        float4 t = v[(size_t)((b<<10)+ls)*64 + d4];
        float wk = w[kk];
        ax += wk*t.x; ay += wk*t.y; az += wk*t.z; aw += wk*t.w;
    }
    storep4(ah, al, gid, make_float4(ax, ay, az, aw));
}

// ---------------- decomp: (pair + f32) - movmean5 -> pair ----------------
__global__ __launch_bounds__(256) void add_decomp_pf_p(const ushort* __restrict__ xah,
                                                       const ushort* __restrict__ xal,
                                                       const float4* __restrict__ xb,
                                                       ushort* __restrict__ oh,
                                                       ushort* __restrict__ ol){
    int d4 = threadIdx.x & 63;
    int rg = threadIdx.x >> 6;
    int b = blockIdx.x;
    int l0 = blockIdx.y*128 + rg*32;
    float4 win[5];
    #pragma unroll
    for (int i=0;i<4;i++){
        int g = l0 - 2 + i;
        g = g < 0 ? 0 : g;
        size_t idx = (size_t)((b<<10) + g)*64 + d4;
        float4 A = loadp4(xah, xal, idx), Bv = xb[idx];
        win[i] = make_float4(A.x+Bv.x, A.y+Bv.y, A.z+Bv.z, A.w+Bv.w);
    }
    for (int i=0;i<32;i++){
        int g = l0 + 2 + i;
        g = g > LL-1 ? LL-1 : g;
        size_t idx = (size_t)((b<<10) + g)*64 + d4;
        float4 A = loadp4(xah, xal, idx), Bv = xb[idx];
        win[4] = make_float4(A.x+Bv.x, A.y+Bv.y, A.z+Bv.z, A.w+Bv.w);
        float4 o;
        o.x = win[2].x - (win[0].x+win[1].x+win[2].x+win[3].x+win[4].x)*0.2f;
        o.y = win[2].y - (win[0].y+win[1].y+win[2].y+win[3].y+win[4].y)*0.2f;
        o.z = win[2].z - (win[0].z+win[1].z+win[2].z+win[3].z+win[4].z)*0.2f;
        o.w = win[2].w - (win[0].w+win[1].w+win[2].w+win[3].w+win[4].w)*0.2f;
        storep4(oh, ol, (size_t)((b<<10) + l0 + i)*64 + d4, o);
        win[0]=win[1]; win[1]=win[2]; win[2]=win[3]; win[3]=win[4];
    }
}

// decomp 3-input: (pair + f32 + f32) - movmean5 -> pair
__global__ __launch_bounds__(256) void add_decomp3_pff_p(const ushort* __restrict__ xah,
                                                         const ushort* __restrict__ xal,
                                                         const float4* __restrict__ xb,
                                                         const float4* __restrict__ xc,
                                                         ushort* __restrict__ oh,
                                                         ushort* __restrict__ ol){
    int d4 = threadIdx.x & 63;
    int rg = threadIdx.x >> 6;
    int b = blockIdx.x;
    int l0 = blockIdx.y*128 + rg*32;
    float4 win[5];
    #pragma unroll
    for (int i=0;i<4;i++){
        int g = l0 - 2 + i;
        g = g < 0 ? 0 : g;
        size_t idx = (size_t)((b<<10) + g)*64 + d4;
        float4 A = loadp4(xah, xal, idx), Bv = xb[idx], Cc = xc[idx];
        win[i] = make_float4(A.x+Bv.x+Cc.x, A.y+Bv.y+Cc.y, A.z+Bv.z+Cc.z, A.w+Bv.w+Cc.w);
    }
    for (int i=0;i<32;i++){
        int g = l0 + 2 + i;
        g = g > LL-1 ? LL-1 : g;
        size_t idx = (size_t)((b<<10) + g)*64 + d4;
        float4 A = loadp4(xah, xal, idx), Bv = xb[idx], Cc = xc[idx];
        win[4] = make_float4(A.x+Bv.x+Cc.x, A.y+Bv.y+Cc.y, A.z+Bv.z+Cc.z, A.w+Bv.w+Cc.w);
        float4 o;
        o.x = win[2].x - (win[0].x+win[1].x+win[2].x+win[3].x+win[4].x)*0.2f;
        o.y = win[2].y - (win[0].y+win[1].y+win[2].y+win[3].y+win[4].y)*0.2f;
        o.z = win[2].z - (win[0].z+win[1].z+win[2].z+win[3].z+win[4].z)*0.2f;
        o.w = win[2].w - (win[0].w+win[1].w+win[2].w+win[3].w+win[4].w)*0.2f;
        storep4(oh, ol, (size_t)((b<<10) + l0 + i)*64 + d4, o);
        win[0]=win[1]; win[1]=win[2]; win[2]=win[3]; win[3]=win[4];
    }
}

// ---------------- layernorm over d per (b,l), pair input ----------------
__global__ __launch_bounds__(256) void ln_kernel(const ushort* __restrict__ xh_,
                                                 const ushort* __restrict__ xl_,
                                                 const float* __restrict__ nw,
                                                 const float* __restrict__ nb,
                                                 float* __restrict__ xh){
    int bl = blockIdx.x, d = threadIdx.x;
    size_t i = (size_t)bl*DM + d;
    float val = h2f(xh_[i]) + h2f(xl_[i])*LINV;
    __shared__ float red[4];
    float v = val;
    for (int o=32;o>0;o>>=1) v += __shfl_down(v, o, 64);
    if ((d&63)==0) red[d>>6] = v;
    __syncthreads();
    float mu = (red[0]+red[1]+red[2]+red[3])*(1.f/256.f);
    __syncthreads();
    float diff = val - mu;
    v = diff*diff;
    for (int o=32;o>0;o>>=1) v += __shfl_down(v, o, 64);
    if ((d&63)==0) red[d>>6] = v;
    __syncthreads();
    float var = (red[0]+red[1]+red[2]+red[3])*(1.f/256.f);
    xh[i] = diff*rsqrtf(var+1e-5f)*nw[d] + nb[d];
}

// ---------------- column sums over l ----------------
__global__ __launch_bounds__(256) void colsum_kernel(const float* __restrict__ xh,
                                                     float* __restrict__ colsum){
    int b = blockIdx.x, chunk = blockIdx.y, d = threadIdx.x;
    float s = 0.f;
    for (int l = chunk*128; l < (chunk+1)*128; l++)
        s += xh[((size_t)b*LL + l)*DM + d];
    atomicAdd(&colsum[b*DM + d], s);
}

// ---------------- g = gelu(xh - colmean) ----------------
__global__ __launch_bounds__(256) void gelu_sub_kernel(const float* __restrict__ xh,
                                                       const float* __restrict__ colsum,
                                                       float* __restrict__ g){
    int bl = blockIdx.x, d = threadIdx.x;
    int b = bl / LL;
    float v = xh[(size_t)bl*DM + d] - colsum[b*DM + d]*(1.f/1024.f);
    g[(size_t)bl*DM + d] = gelu_f(v);
}

// ---------------- final projection ----------------
__global__ __launch_bounds__(256) void proj_kernel(const float* __restrict__ g,
                                                   const float* __restrict__ pw,
                                                   const float* __restrict__ pb,
                                                   float* __restrict__ out){
    int b = blockIdx.x, c = blockIdx.y, ch = blockIdx.z;
    int tid = threadIdx.x;
    const size_t F = (size_t)LL*DM;
    size_t base = ch*(F/16);
    float s = 0.f;
    for (size_t i = tid; i < F/16; i += 256)
        s += g[(size_t)b*F + base + i] * pw[(size_t)c*F + base + i];
    for (int o=32;o>0;o>>=1) s += __shfl_down(s, o, 64);
    __shared__ float red[4];
    if ((tid&63)==0) red[tid>>6] = s;
    __syncthreads();
    if (tid==0){
        float tot = red[0]+red[1]+red[2]+red[3];
        if (ch==0) tot += pb[c];
        atomicAdd(&out[b*3 + c], tot);
    }
}

extern "C" void kernel_launch(void* const* d_in, const int* in_sizes, int n_in,
                              void* d_out, int out_size, void* d_ws, size_t ws_size,
                              hipStream_t stream) {
    const float* x_enc   = (const float*)d_in[0];
    const float* token_w = (const float*)d_in[1];
    const float* qw = (const float*)d_in[2];
    const float* qb = (const float*)d_in[3];
    const float* kw = (const float*)d_in[4];
    const float* kb = (const float*)d_in[5];
    const float* vw = (const float*)d_in[6];
    const float* vb = (const float*)d_in[7];
    const float* ow = (const float*)d_in[8];
    const float* ob = (const float*)d_in[9];
    const float* c1w = (const float*)d_in[10];
    const float* c2w = (const float*)d_in[11];
    const float* norm_w = (const float*)d_in[12];
    const float* norm_b = (const float*)d_in[13];
    const float* proj_w = (const float*)d_in[14];
    const float* proj_b = (const float*)d_in[15];
    float* outp = (float*)d_out;

    const size_t NTOK = (size_t)BB*LL*DM;        // 8388608
    float* ws = (float*)d_ws;
    float* buf0 = ws;            // x pair / y pair
    float* buf1 = ws + NTOK;     // q pair / a pair / x1 pair / ln-out f32
    float* buf2 = ws + 2*NTOK;   // k pair / o f32 / y2 f32 / gelu f32
    ushort* wu = (ushort*)(ws + 3*NTOK);
    const size_t WSM = (size_t)NLAYERS*DM*DM;    // 196608
    const size_t WSF = (size_t)NLAYERS*DFF*DM;   // 786432
    ushort* qkvwh = wu;              ushort* qkvwl = qkvwh + 3*WSM;
    ushort* owh  = qkvwl + 3*WSM;    ushort* owl  = owh + WSM;
    ushort* c1wh = owl + WSM;        ushort* c1wl = c1wh + WSF;
    ushort* c2wh = c1wl + WSF;       ushort* c2wl = c2wh + WSF;
    float* after_w = ws + 3*NTOK + 2359296;
    float* qkvbias = after_w;                       // 3*768
    float* colsum = qkvbias + (size_t)NLAYERS*768;  // 8192
    int*   delays = (int*)(colsum + BB*DM);         // 192
    float* wts    = (float*)(delays + BB*TOPK);     // 192
    int*   cand   = (int*)(wts + BB*TOPK);          // 512
    float* scores4 = (float*)(cand + BB*TOPC);      // 2048
    float* twT    = scores4 + BB*TOPC*4;            // 16128
    float* scr    = twT + 63*256;                   // 524288
    float* buf3   = scr + 524288;                   // v f32 / FFN2 partial f32

    const size_t needed_floats = 3*NTOK + 2359296 + (size_t)NLAYERS*768 + (size_t)BB*DM
                               + (size_t)BB*TOPK*2 + (size_t)BB*TOPC
                               + (size_t)BB*TOPC*4 + 63*256 + 524288 + NTOK;
    const bool zs = (ws_size >= needed_floats*sizeof(float));

    hipMemsetAsync(d_out, 0, 96*sizeof(float), stream);

    {
        int n1 = NLAYERS*DM*DM;
        int n2 = NLAYERS*DFF*DM;
        split_w_strided<<<(n1+255)/256, 256, 0, stream>>>(qw, qkvwh, qkvwl, n1, 65536, 196608, 0);
        split_w_strided<<<(n1+255)/256, 256, 0, stream>>>(kw, qkvwh, qkvwl, n1, 65536, 196608, 65536);
        split_w_strided<<<(n1+255)/256, 256, 0, stream>>>(vw, qkvwh, qkvwl, n1, 65536, 196608, 131072);
        cat_bias3_k<<<(NLAYERS*768+255)/256, 256, 0, stream>>>(qb, kb, vb, qkvbias, NLAYERS*768);
        split_w_k<<<(n1+255)/256, 256, 0, stream>>>(ow, owh, owl, n1);
        split_w_k<<<(n2+255)/256, 256, 0, stream>>>(c1w, c1wh, c1wl, n2);
        split_w_k<<<(n2+255)/256, 256, 0, stream>>>(c2w, c2wh, c2wl, n2);
        transpose_tw<<<(256*63+255)/256, 256, 0, stream>>>(token_w, twT);
    }

    // x pair in buf0
    ushort* xh_p = (ushort*)buf0;  ushort* xl_p = xh_p + NTOK;
    token_embed_k<<<dim3(BB, LL/32), 256, 0, stream>>>(x_enc, twT, xh_p, xl_p);

    const int M = BB*LL;  // 32768
    const int FFNC = 8192;

    for (int l=0; l<NLAYERS; l++){
        ushort* qkvwh_l = qkvwh + (size_t)l*768*DM; ushort* qkvwl_l = qkvwl + (size_t)l*768*DM;
        ushort* owh_l = owh + (size_t)l*DM*DM;      ushort* owl_l = owl + (size_t)l*DM*DM;
        ushort* c1wh_l = c1wh + (size_t)l*DFF*DM;   ushort* c1wl_l = c1wl + (size_t)l*DFF*DM;
        ushort* c2wh_l = c2wh + (size_t)l*DM*DFF;   ushort* c2wl_l = c2wl + (size_t)l*DM*DFF;
        const float* qkvb_l = qkvbias + (size_t)l*768;
        const float* ob_l = ob + (size_t)l*DM;

        // fused q+k+v -> buf1 pair (q), buf2 pair (k), buf3 f32 (v)
        ushort* qh_p = (ushort*)buf1;  ushort* ql_p = qh_p + NTOK;
        ushort* kh_p = (ushort*)buf2;  ushort* kl_p = kh_p + NTOK;
        gemm_mfma_split<true,false,4,false><<<(M/128)*(768/64), 256, 0, stream>>>(
            xh_p, xl_p, qkvwh_l, qkvwl_l, qkvb_l, qh_p, ql_p, kh_p, kl_p, buf3, M, 768, DM);

        // approx corr -> fused reduce+candidates -> exact rescore -> top-6
        corr_mfma<<<2048, 256, 0, stream>>>(qh_p, kh_p, scr);
        corr_sel<<<BB, 256, 0, stream>>>(scr, cand);
        rescore_k<<<dim3(BB*TOPC, 4), 256, 0, stream>>>(qh_p, ql_p, kh_p, kl_p, cand, scores4);
        finalize_k<<<BB, 64, 0, stream>>>(cand, scores4, delays, wts);

        // a pair -> buf1 (q dead), o f32 -> buf2 (k dead)
        ushort* ah_p = (ushort*)buf1;  ushort* al_p = ah_p + NTOK;
        attn_gather4<<<(BB*LL*64)/256, 256, 0, stream>>>(
            (const float4*)buf3, delays, wts, ah_p, al_p);
        gemm_mfma_split<true,false,0,false><<<(M/128)*(DM/64), 256, 0, stream>>>(
            ah_p, al_p, owh_l, owl_l, ob_l, buf2, nullptr, nullptr, nullptr, nullptr, M, DM, DM);

        // x1 pair = (x + o) - movmean -> buf1 (a dead)
        ushort* x1h_p = (ushort*)buf1;  ushort* x1l_p = x1h_p + NTOK;
        add_decomp_pf_p<<<dim3(BB, LL/128), 256, 0, stream>>>(
            xh_p, xl_p, (const float4*)buf2, x1h_p, x1l_p);

        // FFN chunked: y pair in buf0 (x dead); y2 f32 -> buf2 (+ buf3 partial when zs)
        ushort* yh_p = (ushort*)buf0;
        ushort* yl_p = yh_p + (size_t)FFNC*DFF;
        for (int c0 = 0; c0 < M; c0 += FFNC){
            gemm_mfma_split<false,true,2,false><<<(FFNC/128)*(DFF/64), 256, 0, stream>>>(
                x1h_p + (size_t)c0*DM, x1l_p + (size_t)c0*DM, c1wh_l, c1wl_l, nullptr,
                yh_p, yl_p, nullptr, nullptr, nullptr, FFNC, DFF, DM);
            if (zs){
                gemm_mfma_split<false,false,0,true><<<dim3((FFNC/128)*(DM/64), 2), 256, 0, stream>>>(
                    yh_p, yl_p, c2wh_l, c2wl_l, nullptr,
                    buf2 + (size_t)c0*DM, buf3 + (size_t)c0*DM, nullptr, nullptr, nullptr, FFNC, DM, DFF);
            } else {
                gemm_mfma_split<false,false,0,false><<<(FFNC/128)*(DM/64), 256, 0, stream>>>(
                    yh_p, yl_p, c2wh_l, c2wl_l, nullptr,
                    buf2 + (size_t)c0*DM, nullptr, nullptr, nullptr, nullptr, FFNC, DM, DFF);
            }
        }

        // x pair = (x1 + y2 [+partial]) - movmean -> buf0 (y dead)
        if (zs)
            add_decomp3_pff_p<<<dim3(BB, LL/128), 256, 0, stream>>>(
                x1h_p, x1l_p, (const float4*)buf2, (const float4*)buf3, xh_p, xl_p);
        else
            add_decomp_pf_p<<<dim3(BB, LL/128), 256, 0, stream>>>(
                x1h_p, x1l_p, (const float4*)buf2, xh_p, xl_p);
    }

    // final layernorm (pair in) -> buf1 f32
    ln_kernel<<<BB*LL, 256, 0, stream>>>(xh_p, xl_p, norm_w, norm_b, buf1);
    hipMemsetAsync(colsum, 0, (size_t)BB*DM*sizeof(float), stream);
    colsum_kernel<<<dim3(BB, 8), 256, 0, stream>>>(buf1, colsum);
    gelu_sub_kernel<<<BB*LL, 256, 0, stream>>>(buf1, colsum, buf2);
    proj_kernel<<<dim3(BB, 3, 16), 256, 0, stream>>>(buf2, proj_w, proj_b, outp);
}

// Round 19
// 1657.700 us; speedup vs baseline: 1.1108x; 1.0751x over previous
//
#include <hip/hip_runtime.h>
#include <hip/hip_bf16.h>
#include <math.h>

// Problem constants
#define BB 32
#define LL 1024
#define C_IN 21
#define DM 256
#define DFF 1024
#define NLAYERS 3
#define TOPK 6
#define TOPC 16
#define LSCALE 4096.0f
#define LINV (1.0f/4096.0f)

typedef __attribute__((ext_vector_type(8))) short short8v;
typedef __attribute__((ext_vector_type(8))) _Float16 half8;
typedef __attribute__((ext_vector_type(4))) float f32x4;

__device__ __forceinline__ float gelu_f(float v){
    return 0.5f * v * (1.0f + erff(v * 0.7071067811865476f));
}
__device__ __forceinline__ ushort f2h_bits(float f){
    _Float16 h = (_Float16)f;
    return __builtin_bit_cast(ushort, h);
}
__device__ __forceinline__ float h2f(ushort u){
    return (float)__builtin_bit_cast(_Float16, u);
}
// direct global->LDS 16B copy (wave-uniform LDS base + lane*16)
__device__ __forceinline__ void lds16(const ushort* g, ushort* l){
    __builtin_amdgcn_global_load_lds(
        (const __attribute__((address_space(1))) void*)g,
        (__attribute__((address_space(3))) void*)l, 16, 0, 0);
}
// split-pair helpers (4 elements)
__device__ __forceinline__ float4 loadp4(const ushort* __restrict__ h, const ushort* __restrict__ l, size_t i4){
    ushort4 hv = *reinterpret_cast<const ushort4*>(h + 4*i4);
    ushort4 lv = *reinterpret_cast<const ushort4*>(l + 4*i4);
    return make_float4(h2f(hv.x)+h2f(lv.x)*LINV, h2f(hv.y)+h2f(lv.y)*LINV,
                       h2f(hv.z)+h2f(lv.z)*LINV, h2f(hv.w)+h2f(lv.w)*LINV);
}
__device__ __forceinline__ void storep4(ushort* __restrict__ h, ushort* __restrict__ l, size_t i4, float4 v){
    ushort4 hv, lv;
    _Float16 a;
    a=(_Float16)v.x; hv.x=__builtin_bit_cast(ushort,a); lv.x=f2h_bits((v.x-(float)a)*LSCALE);
    a=(_Float16)v.y; hv.y=__builtin_bit_cast(ushort,a); lv.y=f2h_bits((v.y-(float)a)*LSCALE);
    a=(_Float16)v.z; hv.z=__builtin_bit_cast(ushort,a); lv.z=f2h_bits((v.z-(float)a)*LSCALE);
    a=(_Float16)v.w; hv.w=__builtin_bit_cast(ushort,a); lv.w=f2h_bits((v.w-(float)a)*LSCALE);
    *reinterpret_cast<ushort4*>(h + 4*i4) = hv;
    *reinterpret_cast<ushort4*>(l + 4*i4) = lv;
}

// ---------------- weight conversion: f16 hi + 4096*lo ----------------
__global__ __launch_bounds__(256) void split_w_k(const float* __restrict__ src,
                                                 ushort* __restrict__ h, ushort* __restrict__ l, int n){
    int i = blockIdx.x*256 + threadIdx.x;
    if (i < n){
        float f = src[i];
        _Float16 hh = (_Float16)f;
        h[i] = __builtin_bit_cast(ushort, hh);
        l[i] = f2h_bits((f - (float)hh) * LSCALE);
    }
}
__global__ __launch_bounds__(256) void split_w_strided(const float* __restrict__ src,
                                                       ushort* __restrict__ h, ushort* __restrict__ l,
                                                       int n, int src_ls, int dst_ls, int dst_off){
    int i = blockIdx.x*256 + threadIdx.x;
    if (i < n){
        int layer = i / src_ls, r = i % src_ls;
        float f = src[i];
        _Float16 hh = (_Float16)f;
        size_t d = (size_t)layer*dst_ls + dst_off + r;
        h[d] = __builtin_bit_cast(ushort, hh);
        l[d] = f2h_bits((f - (float)hh) * LSCALE);
    }
}
__global__ __launch_bounds__(256) void cat_bias3_k(const float* __restrict__ b1,
                                                   const float* __restrict__ b2,
                                                   const float* __restrict__ b3,
                                                   float* __restrict__ out, int n){ // n = 3*768
    int i = blockIdx.x*256 + threadIdx.x;
    if (i < n){
        int layer = i / 768, c = i % 768;
        out[i] = (c < 256) ? b1[layer*256 + c]
               : (c < 512) ? b2[layer*256 + c - 256]
                           : b3[layer*256 + c - 512];
    }
}
// transpose token weight [256][63] -> [63][256]
__global__ __launch_bounds__(256) void transpose_tw(const float* __restrict__ src,
                                                    float* __restrict__ dst){
    int i = blockIdx.x*256 + threadIdx.x;
    if (i < 256*63){
        int d = i / 63, k = i % 63;
        dst[k*256 + d] = src[i];
    }
}

// ---------------- token embedding: circular conv1d k=3, split-pair output ----------------
__global__ __launch_bounds__(256) void token_embed_k(const float* __restrict__ x,
                                                     const float* __restrict__ wT,
                                                     ushort* __restrict__ oh,
                                                     ushort* __restrict__ ol){
    int b = blockIdx.x, l0 = blockIdx.y*32;
    int d = threadIdx.x;
    __shared__ float xs[34][C_IN];
    for (int i = threadIdx.x; i < 34*C_IN; i += 256){
        int r = i / C_IN, c = i % C_IN;
        int g = (l0 - 1 + r + LL) & (LL-1);
        xs[r][c] = x[(size_t)b*LL*C_IN + (size_t)g*C_IN + c];
    }
    float w[63];
    #pragma unroll
    for (int k=0;k<63;k++) w[k] = wT[k*256 + d];
    __syncthreads();
    for (int i=0;i<32;i++){
        float acc = 0.f;
        #pragma unroll
        for (int c=0;c<C_IN;c++){
            acc += xs[i][c]   * w[c*3+0];
            acc += xs[i+1][c] * w[c*3+1];
            acc += xs[i+2][c] * w[c*3+2];
        }
        size_t idx = ((size_t)b*LL + l0+i)*DM + d;
        _Float16 hh = (_Float16)acc;
        oh[idx] = __builtin_bit_cast(ushort, hh);
        ol[idx] = f2h_bits((acc - (float)hh) * LSCALE);
    }
}

// =================== split-f16 MFMA GEMM, 128x64, double-buffered global_load_lds (2-phase) ===================
// OMODE: 0 = f32 out (Cv), 2 = split pair out (Cv,C2v),
//        4 = fused qkv: col<256 -> q pair (Cv,C2v), col<512 -> k pair (C3v,C4v), else v f32 (C5v)
template<bool BIAS, bool GELU, int OMODE>
__global__ __launch_bounds__(256) void gemm_mfma_split(const ushort* __restrict__ Ah_g,
                                                       const ushort* __restrict__ Al_g,
                                                       const ushort* __restrict__ Wh,
                                                       const ushort* __restrict__ Wl,
                                                       const float* __restrict__ bias,
                                                       void* __restrict__ Cv,
                                                       void* __restrict__ C2v,
                                                       void* __restrict__ C3v,
                                                       void* __restrict__ C4v,
                                                       void* __restrict__ C5v,
                                                       int M, int N, int K){
    __shared__ __align__(16) ushort Ah_s[2][128*32];
    __shared__ __align__(16) ushort Al_s[2][128*32];
    __shared__ __align__(16) ushort Wh_s[2][64*32];
    __shared__ __align__(16) ushort Wl_s[2][64*32];

    const int tid = threadIdx.x;
    const int MB = M >> 7;
    const int bx = blockIdx.x % MB, by = blockIdx.x / MB;
    const int bm = bx << 7, bn = by << 6;

    const int lane = tid & 63;
    const int wid  = tid >> 6;
    const int wm = wid >> 1, wn = wid & 1;
    const int lr = lane & 15, lg = lane >> 4;

    int aoff[4], boff[2];
    #pragma unroll
    for (int f=0; f<4; f++){
        int ar = wm*64 + f*16 + lr;
        aoff[f] = ar*32 + (lg ^ ((ar>>1)&3))*8;
    }
    #pragma unroll
    for (int g=0; g<2; g++){
        int br = wn*32 + g*16 + lr;
        boff[g] = br*32 + (lg ^ ((br>>1)&3))*8;
    }

    f32x4 acc[4][2], accX[4][2];
    #pragma unroll
    for (int i=0;i<4;i++)
        #pragma unroll
        for (int j=0;j<2;j++){
            acc[i][j]  = (f32x4){0.f,0.f,0.f,0.f};
            accX[i][j] = (f32x4){0.f,0.f,0.f,0.f};
        }

    const int wbase = (tid & 192);   // wave-uniform

    auto stage = [&](int bufi, int k0){
        #pragma unroll
        for (int i=0;i<2;i++){
            int c = i*256 + tid;
            int row = c >> 2, ko = c & 3;
            int sw = ko ^ ((row>>1)&3);
            size_t src = (size_t)(bm+row)*K + k0 + sw*8;
            int ldso = (i*256 + wbase)*8;
            lds16(Ah_g + src, &Ah_s[bufi][ldso]);
            lds16(Al_g + src, &Al_s[bufi][ldso]);
        }
        {
            int row = tid >> 2, ko = tid & 3;
            int sw = ko ^ ((row>>1)&3);
            size_t src = (size_t)(bn+row)*K + k0 + sw*8;
            lds16(Wh + src, &Wh_s[bufi][wbase*8]);
            lds16(Wl + src, &Wl_s[bufi][wbase*8]);
        }
    };

    stage(0, 0);
    __syncthreads();

    int cur = 0;
    for (int k0=0; k0<K; k0+=32){
        if (k0 + 32 < K) stage(cur^1, k0+32);   // prefetch next tile (in flight during MFMA)

        short8v af[4], al[4], bf_[2], bl[2];
        #pragma unroll
        for (int f=0; f<4; f++){
            af[f] = *reinterpret_cast<short8v*>(&Ah_s[cur][aoff[f]]);
            al[f] = *reinterpret_cast<short8v*>(&Al_s[cur][aoff[f]]);
        }
        #pragma unroll
        for (int g=0; g<2; g++){
            bf_[g] = *reinterpret_cast<short8v*>(&Wh_s[cur][boff[g]]);
            bl[g]  = *reinterpret_cast<short8v*>(&Wl_s[cur][boff[g]]);
        }
        #pragma unroll
        for (int i=0;i<4;i++){
            #pragma unroll
            for (int j=0;j<2;j++){
                acc[i][j] = __builtin_amdgcn_mfma_f32_16x16x32_f16(
                    __builtin_bit_cast(half8, af[i]), __builtin_bit_cast(half8, bf_[j]), acc[i][j], 0,0,0);
                accX[i][j] = __builtin_amdgcn_mfma_f32_16x16x32_f16(
                    __builtin_bit_cast(half8, af[i]), __builtin_bit_cast(half8, bl[j]), accX[i][j], 0,0,0);
                accX[i][j] = __builtin_amdgcn_mfma_f32_16x16x32_f16(
                    __builtin_bit_cast(half8, al[i]), __builtin_bit_cast(half8, bf_[j]), accX[i][j], 0,0,0);
            }
        }
        __syncthreads();   // drains prefetch (vmcnt) + protects buf reuse
        cur ^= 1;
    }

    // ---- epilogue ----
    const int crow0 = bm + wm*64, ccol0 = bn + wn*32;
    #pragma unroll
    for (int i=0;i<4;i++){
        #pragma unroll
        for (int j=0;j<2;j++){
            int row0 = crow0 + i*16 + lg*4;
            int col  = ccol0 + j*16 + lr;
            float bv = BIAS ? bias[col] : 0.f;
            #pragma unroll
            for (int r=0;r<4;r++){
                float v = acc[i][j][r] + accX[i][j][r]*LINV + bv;
                if (GELU) v = gelu_f(v);
                if (OMODE == 0){
                    ((float*)Cv)[(size_t)(row0+r)*N + col] = v;
                } else if (OMODE == 2){
                    size_t idx = (size_t)(row0+r)*N + col;
                    _Float16 hh = (_Float16)v;
                    ((ushort*)Cv)[idx]  = __builtin_bit_cast(ushort, hh);
                    ((ushort*)C2v)[idx] = f2h_bits((v - (float)hh) * LSCALE);
                } else { // OMODE 4: fused qkv, out stride 256
                    if (col < 512){
                        _Float16 hh = (_Float16)v;
                        ushort hb = __builtin_bit_cast(ushort, hh);
                        ushort lb = f2h_bits((v - (float)hh) * LSCALE);
                        if (col < 256){
                            size_t idx = (size_t)(row0+r)*256 + col;
                            ((ushort*)Cv)[idx]  = hb;
                            ((ushort*)C2v)[idx] = lb;
                        } else {
                            size_t idx = (size_t)(row0+r)*256 + (col-256);
                            ((ushort*)C3v)[idx] = hb;
                            ((ushort*)C4v)[idx] = lb;
                        }
                    } else {
                        ((float*)C5v)[(size_t)(row0+r)*256 + (col-512)] = v;
                    }
                }
            }
        }
    }
}

// =================== corr (APPROX, hi-plane): 128x128 Gram tile, double-buffered staging ===================
__global__ __launch_bounds__(256) void corr_mfma(const ushort* __restrict__ qh,
                                                 const ushort* __restrict__ kh,
                                                 float* __restrict__ scr){
    __shared__ __align__(16) ushort Qh_s[2][128*32];
    __shared__ __align__(16) ushort Kh_s[2][128*32];
    __shared__ float bins[255];

    const int tid = threadIdx.x;
    int flat = blockIdx.x;
    flat = (flat & 7) * 256 + (flat >> 3);   // XCD-aware swizzle
    const int bxt = flat & 7;
    const int byt = (flat >> 3) & 7;
    const int b   = flat >> 6;
    const int bi = bxt * 128, bj = byt * 128;

    for (int i=tid; i<255; i+=256) bins[i] = 0.f;

    const int lane = tid & 63;
    const int wid  = tid >> 6;
    const int wm = wid >> 1, wn = wid & 1;
    const int lr = lane & 15, lg = lane >> 4;

    int aoff[4], boff[4];
    #pragma unroll
    for (int f=0; f<4; f++){
        int ar = wm*64 + f*16 + lr;
        aoff[f] = ar*32 + (lg ^ ((ar>>1)&3))*8;
        int br = wn*64 + f*16 + lr;
        boff[f] = br*32 + (lg ^ ((br>>1)&3))*8;
    }

    f32x4 acc[4][4];
    #pragma unroll
    for (int i=0;i<4;i++)
        #pragma unroll
        for (int j=0;j<4;j++)
            acc[i][j] = (f32x4){0.f,0.f,0.f,0.f};

    const size_t qbase = (size_t)b*LL*DM;
    const int wbase = (tid & 192);

    auto stage = [&](int bufi, int k0){
        #pragma unroll
        for (int i=0;i<2;i++){
            int c = i*256 + tid;
            int row = c >> 2, ko = c & 3;
            int sw = ko ^ ((row>>1)&3);
            size_t qsrc = qbase + (size_t)(bi+row)*DM + k0 + sw*8;
            size_t ksrc = qbase + (size_t)(bj+row)*DM + k0 + sw*8;
            int ldso = (i*256 + wbase)*8;
            lds16(qh + qsrc, &Qh_s[bufi][ldso]);
            lds16(kh + ksrc, &Kh_s[bufi][ldso]);
        }
    };

    stage(0, 0);
    __syncthreads();

    int cur = 0;
    for (int k0=0; k0<DM; k0+=32){
        if (k0 + 32 < DM) stage(cur^1, k0+32);

        short8v ah[4], bh4[4];
        #pragma unroll
        for (int f=0; f<4; f++){
            ah[f]  = *reinterpret_cast<short8v*>(&Qh_s[cur][aoff[f]]);
            bh4[f] = *reinterpret_cast<short8v*>(&Kh_s[cur][boff[f]]);
        }
        #pragma unroll
        for (int i=0;i<4;i++)
            #pragma unroll
            for (int j=0;j<4;j++)
                acc[i][j] = __builtin_amdgcn_mfma_f32_16x16x32_f16(
                    __builtin_bit_cast(half8, ah[i]), __builtin_bit_cast(half8, bh4[j]), acc[i][j], 0,0,0);
        __syncthreads();
        cur ^= 1;
    }

    float pre[7][4];
    #pragma unroll
    for (int d=0; d<7; d++)
        #pragma unroll
        for (int r=0;r<4;r++) pre[d][r]=0.f;
    #pragma unroll
    for (int i=0;i<4;i++)
        #pragma unroll
        for (int j=0;j<4;j++)
            #pragma unroll
            for (int r=0;r<4;r++)
                pre[i-j+3][r] += acc[i][j][r];
    const int bbase = wm*64 - wn*64 + lg*4 - lr + 127;
    #pragma unroll
    for (int d=0; d<7; d++)
        #pragma unroll
        for (int r=0;r<4;r++)
            atomicAdd(&bins[bbase + 16*(d-3) + r], pre[d][r]);
    __syncthreads();
    float* slot = scr + ((size_t)(b*64 + byt*8 + bxt) << 8);
    for (int i=tid; i<255; i+=256) slot[i] = bins[i];
}

// ---------------- fused: deterministic tile-bin reduce + top-16 candidates ----------------
__global__ __launch_bounds__(256) void corr_sel(const float* __restrict__ scr,
                                                int* __restrict__ cand){
    int b = blockIdx.x, tid = threadIdx.x;
    __shared__ float sv[LL];
    __shared__ float rv[256];
    __shared__ int ri[256];
    const float* base = scr + ((size_t)b << 14);
    for (int t = tid; t < LL; t += 256){
        float s = 0.f;
        #pragma unroll
        for (int byt=0; byt<8; byt++){
            #pragma unroll
            for (int bxt=0; bxt<8; bxt++){
                int i = (t - 128*(bxt - byt) + 127) & (LL-1);
                if (i < 255) s += base[((byt*8 + bxt) << 8) + i];
            }
        }
        sv[t] = s * (1.f/256.f);
    }
    __syncthreads();
    for (int it=0; it<TOPC; it++){
        float best = -1e30f; int bi = LL;
        for (int i=tid;i<LL;i+=256){
            float v = sv[i];
            if (v > best || (v == best && i < bi)){ best = v; bi = i; }
        }
        rv[tid]=best; ri[tid]=bi;
        __syncthreads();
        for (int s=128;s>0;s>>=1){
            if (tid < s){
                if (rv[tid+s] > rv[tid] || (rv[tid+s]==rv[tid] && ri[tid+s]<ri[tid])){
                    rv[tid]=rv[tid+s]; ri[tid]=ri[tid+s];
                }
            }
            __syncthreads();
        }
        if (tid==0){ cand[b*TOPC+it]=ri[0]; sv[ri[0]] = -1e30f; }
        __syncthreads();
    }
}

// ---------------- exact rescore, k-shared: block=(b, chunk of 16); all 16 cands per block ----------------
// scores16[(b*TOPC+c)*16 + chunk] = Kahan partial over m in [chunk*16384, (chunk+1)*16384)
__global__ __launch_bounds__(256) void rescore_k(const ushort* __restrict__ qh,
                                                 const ushort* __restrict__ ql,
                                                 const ushort* __restrict__ kh,
                                                 const ushort* __restrict__ kl,
                                                 const int* __restrict__ cand,
                                                 float* __restrict__ scores16){
    int b = blockIdx.x;
    int chunk = blockIdx.y;
    __shared__ int offs[TOPC];
    if (threadIdx.x < TOPC) offs[threadIdx.x] = cand[b*TOPC + threadIdx.x] << 8;
    __syncthreads();
    const size_t base = (size_t)b << 18;
    const int mbeg = chunk << 14;          // 16384 elems per chunk
    const int mend = mbeg + (1<<14);
    float s[TOPC], comp[TOPC];
    #pragma unroll
    for (int c=0;c<TOPC;c++){ s[c]=0.f; comp[c]=0.f; }
    for (int m = mbeg + threadIdx.x*8; m < mend; m += 256*8){
        short8v kh8 = *reinterpret_cast<const short8v*>(kh + base + m);
        short8v kl8 = *reinterpret_cast<const short8v*>(kl + base + m);
        float kf[8];
        #pragma unroll
        for (int j=0;j<8;j++)
            kf[j] = h2f((ushort)kh8[j]) + h2f((ushort)kl8[j])*LINV;
        #pragma unroll
        for (int c=0;c<TOPC;c++){
            int mq = (m + offs[c]) & ((1<<18)-1);
            short8v qh8 = *reinterpret_cast<const short8v*>(qh + base + mq);
            short8v ql8 = *reinterpret_cast<const short8v*>(ql + base + mq);
            float term = 0.f;
            #pragma unroll
            for (int j=0;j<8;j++)
                term += kf[j] * (h2f((ushort)qh8[j]) + h2f((ushort)ql8[j])*LINV);
            float y = term - comp[c];
            float tt = s[c] + y;
            comp[c] = (tt - s[c]) - y;
            s[c] = tt;
        }
    }
    __shared__ float red[4];
    #pragma unroll
    for (int c=0;c<TOPC;c++){
        float v = s[c];
        for (int o=32;o>0;o>>=1) v += __shfl_down(v, o, 64);
        if ((threadIdx.x & 63)==0) red[threadIdx.x>>6] = v;
        __syncthreads();
        if (threadIdx.x==0)
            scores16[((size_t)b*TOPC + c)*16 + chunk] = red[0]+red[1]+red[2]+red[3];
        __syncthreads();
    }
}

// ---------------- final top-6 + softmax from exact scores (wave-parallel) ----------------
__global__ __launch_bounds__(64) void finalize_k(const int* __restrict__ cand,
                                                 const float* __restrict__ scores16,
                                                 int* __restrict__ delays,
                                                 float* __restrict__ wts){
    int b = blockIdx.x;
    int lane = threadIdx.x;
    float v = -1e30f;
    int idx = 1<<30;
    if (lane < TOPC){
        size_t s16 = ((size_t)b*TOPC + lane)*16;
        float acc = 0.f;
        #pragma unroll
        for (int ch=0; ch<16; ch++) acc += scores16[s16+ch];
        v = acc * (1.f/256.f);
        idx = cand[b*TOPC + lane];
    }
    float topv[TOPK]; int topi[TOPK];
    #pragma unroll
    for (int k=0;k<TOPK;k++){
        float bv = v; int bi = idx;
        #pragma unroll
        for (int o=8;o>0;o>>=1){
            float ov = __shfl_xor(bv, o, 16);
            int   oi = __shfl_xor(bi, o, 16);
            if (ov > bv || (ov == bv && oi < bi)){ bv = ov; bi = oi; }
        }
        topv[k]=bv; topi[k]=bi;
        if (idx == bi) v = -1e30f;
    }
    if (lane==0){
        float mx = topv[0];
        float e[TOPK], se=0.f;
        #pragma unroll
        for (int k=0;k<TOPK;k++){ e[k]=expf(topv[k]-mx); se+=e[k]; }
        #pragma unroll
        for (int k=0;k<TOPK;k++){
            wts[b*TOPK+k] = e[k]/se;
            delays[b*TOPK+k] = topi[k];
        }
    }
}

// ---------------- attention gather: v f32 -> a split pair ----------------
__global__ __launch_bounds__(256) void attn_gather4(const float4* __restrict__ v,
                                                    const int* __restrict__ delays,
                                                    const float* __restrict__ wts,
                                                    ushort* __restrict__ ah,
                                                    ushort* __restrict__ al){
    int gid = blockIdx.x*256 + threadIdx.x;
    int d4 = gid & 63;
    int bl = gid >> 6;
    int b = bl >> 10, l = bl & (LL-1);
    const int* dl = delays + b*TOPK;
    const float* w = wts + b*TOPK;
    float ax=0.f, ay=0.f, az=0.f, aw=0.f;
    #pragma unroll
    for (int kk=0;kk<TOPK;kk++){
        int ls = (l + dl[kk]) & (LL-1);
        float4 t = v[(size_t)((b<<10)+ls)*64 + d4];
        float wk = w[kk];
        ax += wk*t.x; ay += wk*t.y; az += wk*t.z; aw += wk*t.w;
    }
    storep4(ah, al, gid, make_float4(ax, ay, az, aw));
}

// ---------------- decomp: (pair + f32) - movmean5 -> pair ----------------
__global__ __launch_bounds__(256) void add_decomp_pf_p(const ushort* __restrict__ xah,
                                                       const ushort* __restrict__ xal,
                                                       const float4* __restrict__ xb,
                                                       ushort* __restrict__ oh,
                                                       ushort* __restrict__ ol){
    int d4 = threadIdx.x & 63;
    int rg = threadIdx.x >> 6;
    int b = blockIdx.x;
    int l0 = blockIdx.y*128 + rg*32;
    float4 win[5];
    #pragma unroll
    for (int i=0;i<4;i++){
        int g = l0 - 2 + i;
        g = g < 0 ? 0 : g;
        size_t idx = (size_t)((b<<10) + g)*64 + d4;
        float4 A = loadp4(xah, xal, idx), Bv = xb[idx];
        win[i] = make_float4(A.x+Bv.x, A.y+Bv.y, A.z+Bv.z, A.w+Bv.w);
    }
    for (int i=0;i<32;i++){
        int g = l0 + 2 + i;
        g = g > LL-1 ? LL-1 : g;
        size_t idx = (size_t)((b<<10) + g)*64 + d4;
        float4 A = loadp4(xah, xal, idx), Bv = xb[idx];
        win[4] = make_float4(A.x+Bv.x, A.y+Bv.y, A.z+Bv.z, A.w+Bv.w);
        float4 o;
        o.x = win[2].x - (win[0].x+win[1].x+win[2].x+win[3].x+win[4].x)*0.2f;
        o.y = win[2].y - (win[0].y+win[1].y+win[2].y+win[3].y+win[4].y)*0.2f;
        o.z = win[2].z - (win[0].z+win[1].z+win[2].z+win[3].z+win[4].z)*0.2f;
        o.w = win[2].w - (win[0].w+win[1].w+win[2].w+win[3].w+win[4].w)*0.2f;
        storep4(oh, ol, (size_t)((b<<10) + l0 + i)*64 + d4, o);
        win[0]=win[1]; win[1]=win[2]; win[2]=win[3]; win[3]=win[4];
    }
}

// ---------------- layernorm over d per (b,l), pair input ----------------
__global__ __launch_bounds__(256) void ln_kernel(const ushort* __restrict__ xh_,
                                                 const ushort* __restrict__ xl_,
                                                 const float* __restrict__ nw,
                                                 const float* __restrict__ nb,
                                                 float* __restrict__ xh){
    int bl = blockIdx.x, d = threadIdx.x;
    size_t i = (size_t)bl*DM + d;
    float val = h2f(xh_[i]) + h2f(xl_[i])*LINV;
    __shared__ float red[4];
    float v = val;
    for (int o=32;o>0;o>>=1) v += __shfl_down(v, o, 64);
    if ((d&63)==0) red[d>>6] = v;
    __syncthreads();
    float mu = (red[0]+red[1]+red[2]+red[3])*(1.f/256.f);
    __syncthreads();
    float diff = val - mu;
    v = diff*diff;
    for (int o=32;o>0;o>>=1) v += __shfl_down(v, o, 64);
    if ((d&63)==0) red[d>>6] = v;
    __syncthreads();
    float var = (red[0]+red[1]+red[2]+red[3])*(1.f/256.f);
    xh[i] = diff*rsqrtf(var+1e-5f)*nw[d] + nb[d];
}

// ---------------- column sums over l ----------------
__global__ __launch_bounds__(256) void colsum_kernel(const float* __restrict__ xh,
                                                     float* __restrict__ colsum){
    int b = blockIdx.x, chunk = blockIdx.y, d = threadIdx.x;
    float s = 0.f;
    for (int l = chunk*128; l < (chunk+1)*128; l++)
        s += xh[((size_t)b*LL + l)*DM + d];
    atomicAdd(&colsum[b*DM + d], s);
}

// ---------------- g = gelu(xh - colmean) ----------------
__global__ __launch_bounds__(256) void gelu_sub_kernel(const float* __restrict__ xh,
                                                       const float* __restrict__ colsum,
                                                       float* __restrict__ g){
    int bl = blockIdx.x, d = threadIdx.x;
    int b = bl / LL;
    float v = xh[(size_t)bl*DM + d] - colsum[b*DM + d]*(1.f/1024.f);
    g[(size_t)bl*DM + d] = gelu_f(v);
}

// ---------------- final projection ----------------
__global__ __launch_bounds__(256) void proj_kernel(const float* __restrict__ g,
                                                   const float* __restrict__ pw,
                                                   const float* __restrict__ pb,
                                                   float* __restrict__ out){
    int b = blockIdx.x, c = blockIdx.y, ch = blockIdx.z;
    int tid = threadIdx.x;
    const size_t F = (size_t)LL*DM;
    size_t base = ch*(F/16);
    float s = 0.f;
    for (size_t i = tid; i < F/16; i += 256)
        s += g[(size_t)b*F + base + i] * pw[(size_t)c*F + base + i];
    for (int o=32;o>0;o>>=1) s += __shfl_down(s, o, 64);
    __shared__ float red[4];
    if ((tid&63)==0) red[tid>>6] = s;
    __syncthreads();
    if (tid==0){
        float tot = red[0]+red[1]+red[2]+red[3];
        if (ch==0) tot += pb[c];
        atomicAdd(&out[b*3 + c], tot);
    }
}

extern "C" void kernel_launch(void* const* d_in, const int* in_sizes, int n_in,
                              void* d_out, int out_size, void* d_ws, size_t ws_size,
                              hipStream_t stream) {
    const float* x_enc   = (const float*)d_in[0];
    const float* token_w = (const float*)d_in[1];
    const float* qw = (const float*)d_in[2];
    const float* qb = (const float*)d_in[3];
    const float* kw = (const float*)d_in[4];
    const float* kb = (const float*)d_in[5];
    const float* vw = (const float*)d_in[6];
    const float* vb = (const float*)d_in[7];
    const float* ow = (const float*)d_in[8];
    const float* ob = (const float*)d_in[9];
    const float* c1w = (const float*)d_in[10];
    const float* c2w = (const float*)d_in[11];
    const float* norm_w = (const float*)d_in[12];
    const float* norm_b = (const float*)d_in[13];
    const float* proj_w = (const float*)d_in[14];
    const float* proj_b = (const float*)d_in[15];
    float* outp = (float*)d_out;

    const size_t NTOK = (size_t)BB*LL*DM;        // 8388608
    float* ws = (float*)d_ws;
    float* buf0 = ws;            // x pair / y hi
    float* buf1 = ws + NTOK;     // q pair / a pair / x1 pair / ln-out f32
    float* buf2 = ws + 2*NTOK;   // k pair / o f32 / y2 f32 / gelu f32
    ushort* wu = (ushort*)(ws + 3*NTOK);
    const size_t WSM = (size_t)NLAYERS*DM*DM;    // 196608
    const size_t WSF = (size_t)NLAYERS*DFF*DM;   // 786432
    ushort* qkvwh = wu;              ushort* qkvwl = qkvwh + 3*WSM;
    ushort* owh  = qkvwl + 3*WSM;    ushort* owl  = owh + WSM;
    ushort* c1wh = owl + WSM;        ushort* c1wl = c1wh + WSF;
    ushort* c2wh = c1wl + WSF;       ushort* c2wl = c2wh + WSF;
    float* after_w = ws + 3*NTOK + 2359296;
    float* qkvbias = after_w;                       // 3*768
    float* colsum = qkvbias + (size_t)NLAYERS*768;  // 8192
    int*   delays = (int*)(colsum + BB*DM);         // 192
    float* wts    = (float*)(delays + BB*TOPK);     // 192
    int*   cand   = (int*)(wts + BB*TOPK);          // 512
    float* scores16 = (float*)(cand + BB*TOPC);     // 8192
    float* twT    = scores16 + BB*TOPC*16;          // 16128
    float* scr    = twT + 63*256;                   // 524288
    float* buf3   = scr + 524288;                   // v f32 / y lo (NTOK floats)

    hipMemsetAsync(d_out, 0, 96*sizeof(float), stream);

    {
        int n1 = NLAYERS*DM*DM;
        int n2 = NLAYERS*DFF*DM;
        split_w_strided<<<(n1+255)/256, 256, 0, stream>>>(qw, qkvwh, qkvwl, n1, 65536, 196608, 0);
        split_w_strided<<<(n1+255)/256, 256, 0, stream>>>(kw, qkvwh, qkvwl, n1, 65536, 196608, 65536);
        split_w_strided<<<(n1+255)/256, 256, 0, stream>>>(vw, qkvwh, qkvwl, n1, 65536, 196608, 131072);
        cat_bias3_k<<<(NLAYERS*768+255)/256, 256, 0, stream>>>(qb, kb, vb, qkvbias, NLAYERS*768);
        split_w_k<<<(n1+255)/256, 256, 0, stream>>>(ow, owh, owl, n1);
        split_w_k<<<(n2+255)/256, 256, 0, stream>>>(c1w, c1wh, c1wl, n2);
        split_w_k<<<(n2+255)/256, 256, 0, stream>>>(c2w, c2wh, c2wl, n2);
        transpose_tw<<<(256*63+255)/256, 256, 0, stream>>>(token_w, twT);
    }

    // x pair in buf0
    ushort* xh_p = (ushort*)buf0;  ushort* xl_p = xh_p + NTOK;
    token_embed_k<<<dim3(BB, LL/32), 256, 0, stream>>>(x_enc, twT, xh_p, xl_p);

    const int M = BB*LL;   // 32768
    const int FFNC = 16384;

    for (int l=0; l<NLAYERS; l++){
        ushort* qkvwh_l = qkvwh + (size_t)l*768*DM; ushort* qkvwl_l = qkvwl + (size_t)l*768*DM;
        ushort* owh_l = owh + (size_t)l*DM*DM;      ushort* owl_l = owl + (size_t)l*DM*DM;
        ushort* c1wh_l = c1wh + (size_t)l*DFF*DM;   ushort* c1wl_l = c1wl + (size_t)l*DFF*DM;
        ushort* c2wh_l = c2wh + (size_t)l*DM*DFF;   ushort* c2wl_l = c2wl + (size_t)l*DM*DFF;
        const float* qkvb_l = qkvbias + (size_t)l*768;
        const float* ob_l = ob + (size_t)l*DM;

        // fused q+k+v -> buf1 pair (q), buf2 pair (k), buf3 f32 (v)
        ushort* qh_p = (ushort*)buf1;  ushort* ql_p = qh_p + NTOK;
        ushort* kh_p = (ushort*)buf2;  ushort* kl_p = kh_p + NTOK;
        gemm_mfma_split<true,false,4><<<(M/128)*(768/64), 256, 0, stream>>>(
            xh_p, xl_p, qkvwh_l, qkvwl_l, qkvb_l, qh_p, ql_p, kh_p, kl_p, buf3, M, 768, DM);

        // approx corr -> fused reduce+candidates -> exact rescore (k-shared) -> top-6
        corr_mfma<<<2048, 256, 0, stream>>>(qh_p, kh_p, scr);
        corr_sel<<<BB, 256, 0, stream>>>(scr, cand);
        rescore_k<<<dim3(BB, 16), 256, 0, stream>>>(qh_p, ql_p, kh_p, kl_p, cand, scores16);
        finalize_k<<<BB, 64, 0, stream>>>(cand, scores16, delays, wts);

        // a pair -> buf1 (q dead), o f32 -> buf2 (k dead)
        ushort* ah_p = (ushort*)buf1;  ushort* al_p = ah_p + NTOK;
        attn_gather4<<<(BB*LL*64)/256, 256, 0, stream>>>(
            (const float4*)buf3, delays, wts, ah_p, al_p);
        gemm_mfma_split<true,false,0><<<(M/128)*(DM/64), 256, 0, stream>>>(
            ah_p, al_p, owh_l, owl_l, ob_l, buf2, nullptr, nullptr, nullptr, nullptr, M, DM, DM);

        // x1 pair = (x + o) - movmean -> buf1 (a dead)
        ushort* x1h_p = (ushort*)buf1;  ushort* x1l_p = x1h_p + NTOK;
        add_decomp_pf_p<<<dim3(BB, LL/128), 256, 0, stream>>>(
            xh_p, xl_p, (const float4*)buf2, x1h_p, x1l_p);

        // FFN: 2 chunks of 16384 rows; y hi in buf0 (x dead), y lo in buf3 (v dead); y2 f32 -> buf2
        ushort* yh_p = (ushort*)buf0;
        ushort* yl_p = (ushort*)buf3;
        for (int c0 = 0; c0 < M; c0 += FFNC){
            gemm_mfma_split<false,true,2><<<(FFNC/128)*(DFF/64), 256, 0, stream>>>(
                x1h_p + (size_t)c0*DM, x1l_p + (size_t)c0*DM, c1wh_l, c1wl_l, nullptr,
                yh_p, yl_p, nullptr, nullptr, nullptr, FFNC, DFF, DM);
            gemm_mfma_split<false,false,0><<<(FFNC/128)*(DM/64), 256, 0, stream>>>(
                yh_p, yl_p, c2wh_l, c2wl_l, nullptr,
                buf2 + (size_t)c0*DM, nullptr, nullptr, nullptr, nullptr, FFNC, DM, DFF);
        }

        // x pair = (x1 + y2) - movmean -> buf0 (y hi dead)
        add_decomp_pf_p<<<dim3(BB, LL/128), 256, 0, stream>>>(
            x1h_p, x1l_p, (const float4*)buf2, xh_p, xl_p);
    }

    // final layernorm (pair in) -> buf1 f32
    ln_kernel<<<BB*LL, 256, 0, stream>>>(xh_p, xl_p, norm_w, norm_b, buf1);
    hipMemsetAsync(colsum, 0, (size_t)BB*DM*sizeof(float), stream);
    colsum_kernel<<<dim3(BB, 8), 256, 0, stream>>>(buf1, colsum);
    gelu_sub_kernel<<<BB*LL, 256, 0, stream>>>(buf1, colsum, buf2);
    proj_kernel<<<dim3(BB, 3, 16), 256, 0, stream>>>(buf2, proj_w, proj_b, outp);
}